// Round 12
// baseline (433.882 us; speedup 1.0000x reference)
//
#include <hip/hip_runtime.h>

#define B_ 4
#define T_ 4096
#define D_ 2048
#define H_ 16
#define DK_ 64
#define DV_ 128
#define HDK 1024
#define HDV 2048
#define NN 3072
#define MM 16384
#define NT_ 32  // D_/64 K-tiles (BK=64)

typedef unsigned short u16;
typedef unsigned int u32;
typedef __attribute__((ext_vector_type(8))) short bf16x8;
typedef __attribute__((ext_vector_type(4))) float f32x4;

typedef const __attribute__((address_space(1))) u16 gu16;
typedef __attribute__((address_space(3))) u16 lu16;

__device__ __forceinline__ float b2f(u16 u) {
  u32 x = ((u32)u) << 16; float f; __builtin_memcpy(&f, &x, 4); return f;
}
__device__ __forceinline__ u16 f2b(float f) {
  u32 x; __builtin_memcpy(&x, &f, 4);
  u32 r = x + 0x7FFFu + ((x >> 16) & 1u);
  return (u16)(r >> 16);
}
__device__ __forceinline__ float fexp(float x) { return exp2f(x * 1.44269504f); }
__device__ __forceinline__ float flogsig(float z) {
  float u = exp2f(-fabsf(z) * 1.44269504f);
  float l = log2f(1.f + u) * 0.69314718f;
  return fminf(z, 0.f) - l;
}

// K1: convert [k_w; v_w] (3072 x 2048 f32) -> bf16
__global__ __launch_bounds__(256) void k_cvtw(const float* __restrict__ kw,
                                              const float* __restrict__ vw,
                                              u16* __restrict__ Wb) {
  int i = blockIdx.x * 256 + threadIdx.x;
  size_t e = (size_t)i * 8;
  const float* src = (e < (size_t)HDK * D_) ? (kw + e) : (vw + (e - (size_t)HDK * D_));
  float4 f0 = ((const float4*)src)[0];
  float4 f1 = ((const float4*)src)[1];
  union { int4 v; u16 u[8]; } o;
  o.u[0] = f2b(f0.x); o.u[1] = f2b(f0.y); o.u[2] = f2b(f0.z); o.u[3] = f2b(f0.w);
  o.u[4] = f2b(f1.x); o.u[5] = f2b(f1.y); o.u[6] = f2b(f1.z); o.u[7] = f2b(f1.w);
  *(int4*)(Wb + e) = o.v;
}

// K2: RMSNorm -> x (bf16), and y = x @ gk_w1^T (f32, 16 per row). 4 rows/block.
// (R3/R5-proven version.)
__global__ __launch_bounds__(256) void k_rms(const float* __restrict__ hs,
                                             const float* __restrict__ nw,
                                             const float* __restrict__ w1,
                                             u16* __restrict__ xb,
                                             float* __restrict__ y) {
  int r0 = blockIdx.x * 4;
  int tid = threadIdx.x;
  int wv = tid >> 6, ln = tid & 63;
  __shared__ float red[4][4];
  __shared__ float ys[4][4][16];
  float x[4][8];
  float ssq[4];
  #pragma unroll
  for (int r = 0; r < 4; ++r) {
    const float4* hp = (const float4*)(hs + (size_t)(r0 + r) * D_);
    float4 a = hp[tid * 2], b = hp[tid * 2 + 1];
    x[r][0] = a.x; x[r][1] = a.y; x[r][2] = a.z; x[r][3] = a.w;
    x[r][4] = b.x; x[r][5] = b.y; x[r][6] = b.z; x[r][7] = b.w;
    float s = 0.f;
    #pragma unroll
    for (int i = 0; i < 8; ++i) s += x[r][i] * x[r][i];
    #pragma unroll
    for (int o = 32; o > 0; o >>= 1) s += __shfl_xor(s, o, 64);
    ssq[r] = s;
  }
  if (ln == 0) {
    #pragma unroll
    for (int r = 0; r < 4; ++r) red[wv][r] = ssq[r];
  }
  __syncthreads();
  const float4* np_ = (const float4*)nw;
  float4 n0 = np_[tid * 2], n1 = np_[tid * 2 + 1];
  float nwv[8] = {n0.x, n0.y, n0.z, n0.w, n1.x, n1.y, n1.z, n1.w};
  #pragma unroll
  for (int r = 0; r < 4; ++r) {
    float tot = red[0][r] + red[1][r] + red[2][r] + red[3][r];
    float inv = rsqrtf(tot * (1.f / D_) + 1e-5f);
    union { int4 v; u16 u[8]; } o;
    #pragma unroll
    for (int i = 0; i < 8; ++i) { x[r][i] = x[r][i] * inv * nwv[i]; o.u[i] = f2b(x[r][i]); }
    *(int4*)(xb + (size_t)(r0 + r) * D_ + tid * 8) = o.v;
  }
  float p[4][16];
  #pragma unroll
  for (int r = 0; r < 4; ++r)
    #pragma unroll
    for (int j = 0; j < 16; ++j) p[r][j] = 0.f;
  #pragma unroll
  for (int j = 0; j < 16; ++j) {
    const float4* wp = (const float4*)(w1 + (size_t)j * D_);
    float4 a = wp[tid * 2], b = wp[tid * 2 + 1];
    float wj[8] = {a.x, a.y, a.z, a.w, b.x, b.y, b.z, b.w};
    #pragma unroll
    for (int r = 0; r < 4; ++r) {
      float s = 0.f;
      #pragma unroll
      for (int i = 0; i < 8; ++i) s += x[r][i] * wj[i];
      p[r][j] = s;
    }
  }
  #pragma unroll
  for (int r = 0; r < 4; ++r)
    #pragma unroll
    for (int j = 0; j < 16; ++j) {
      float s = p[r][j];
      #pragma unroll
      for (int o = 32; o > 0; o >>= 1) s += __shfl_xor(s, o, 64);
      p[r][j] = s;
    }
  if (ln == 0) {
    for (int r = 0; r < 4; ++r)
      for (int j = 0; j < 16; ++j) ys[wv][r][j] = p[r][j];
  }
  __syncthreads();
  if (tid < 64) {
    int r = tid >> 4, j = tid & 15;
    y[(size_t)(r0 + r) * 16 + j] = ys[0][r][j] + ys[1][r][j] + ys[2][r][j] + ys[3][r][j];
  }
}

// K3: kv = x @ Wb^T. 256x256 tile, 8 waves, BK=64.
// NEW (R12): B-operand loaded global(L2)->registers directly; LDS holds A only
// (64 KB, 2dbuf x 2kh). Per-tile VMEM issue order:
//   [P0: A-kh0-stage(2)] [P1-end: b0-reload(4)] [P2: A-kh1-stage(2)] [P3-end: b1(4)]
// vmcnt(6) at P0 (newer = A-kh1+b1 of this tile) and P2 (newer = A-kh0+b0 of
// next tile); last tile P2 -> vmcnt(0). b0/b1 reloaded right after last use.
#define GLDS(SRC, DST) __builtin_amdgcn_global_load_lds((gu16*)(SRC), (lu16*)(DST), 16, 0, 0)

#define MFMA16B(AF, BB, MB) do {                                               \
    __builtin_amdgcn_s_setprio(1);                                             \
    _Pragma("unroll")                                                          \
    for (int mi_ = 0; mi_ < 4; ++mi_)                                          \
      _Pragma("unroll")                                                        \
      for (int ni_ = 0; ni_ < 4; ++ni_)                                        \
        acc[(MB) + mi_][ni_] = __builtin_amdgcn_mfma_f32_16x16x32_bf16(        \
            AF[mi_], BB[ni_], acc[(MB) + mi_][ni_], 0, 0, 0);                  \
    __builtin_amdgcn_s_setprio(0);                                             \
    __builtin_amdgcn_sched_barrier(0);                                         \
  } while (0)

#define KTILEB(DB, NB, VM0, VM2, ST) do {                                      \
    /* P0: wait, read kh0 a-frags 0-3, stage A-kh0', MFMA (b0) */              \
    asm volatile("s_waitcnt vmcnt(" VM0 ")" ::: "memory");                     \
    __builtin_amdgcn_s_barrier();                                              \
    __builtin_amdgcn_sched_barrier(0);                                         \
    _Pragma("unroll")                                                          \
    for (int mi_ = 0; mi_ < 4; ++mi_)                                          \
      af[mi_] = *(const bf16x8*)&SA[DB][0][(wr * 128 + mi_ * 16 + r) * 32 + kcol]; \
    if (ST) { GLDS(An, &SA[NB][0][lw]); GLDS(An + 16 * D_, &SA[NB][0][lw + 512]); } \
    __builtin_amdgcn_sched_barrier(0);                                         \
    asm volatile("s_waitcnt lgkmcnt(0)" ::: "memory");                         \
    __builtin_amdgcn_sched_barrier(0);                                         \
    MFMA16B(af, b0, 0);                                                        \
    /* P1: read a-frags 4-7 kh0, MFMA (b0), then reload b0 <- next tile kh0 */ \
    _Pragma("unroll")                                                          \
    for (int mi_ = 0; mi_ < 4; ++mi_)                                          \
      af2[mi_] = *(const bf16x8*)&SA[DB][0][(wr * 128 + (4 + mi_) * 16 + r) * 32 + kcol]; \
    asm volatile("s_waitcnt lgkmcnt(0)" ::: "memory");                         \
    __builtin_amdgcn_sched_barrier(0);                                         \
    MFMA16B(af2, b0, 4);                                                       \
    if (ST) {                                                                  \
      _Pragma("unroll")                                                        \
      for (int ni_ = 0; ni_ < 4; ++ni_)                                        \
        b0[ni_] = *(const bf16x8*)(Wn + (size_t)ni_ * 16 * D_);                \
      __builtin_amdgcn_sched_barrier(0);                                       \
    }                                                                          \
    /* P2: wait, read kh1 a-frags 0-3, stage A-kh1', MFMA (b1) */              \
    asm volatile("s_waitcnt vmcnt(" VM2 ")" ::: "memory");                     \
    __builtin_amdgcn_s_barrier();                                              \
    __builtin_amdgcn_sched_barrier(0);                                         \
    _Pragma("unroll")                                                          \
    for (int mi_ = 0; mi_ < 4; ++mi_)                                          \
      af[mi_] = *(const bf16x8*)&SA[DB][1][(wr * 128 + mi_ * 16 + r) * 32 + kcol]; \
    if (ST) { GLDS(An + 32, &SA[NB][1][lw]); GLDS(An + 32 + 16 * D_, &SA[NB][1][lw + 512]); } \
    __builtin_amdgcn_sched_barrier(0);                                         \
    asm volatile("s_waitcnt lgkmcnt(0)" ::: "memory");                         \
    __builtin_amdgcn_sched_barrier(0);                                         \
    MFMA16B(af, b1, 0);                                                        \
    /* P3: read a-frags 4-7 kh1, MFMA (b1), then reload b1 <- next tile kh1 */ \
    _Pragma("unroll")                                                          \
    for (int mi_ = 0; mi_ < 4; ++mi_)                                          \
      af2[mi_] = *(const bf16x8*)&SA[DB][1][(wr * 128 + (4 + mi_) * 16 + r) * 32 + kcol]; \
    asm volatile("s_waitcnt lgkmcnt(0)" ::: "memory");                         \
    __builtin_amdgcn_sched_barrier(0);                                         \
    MFMA16B(af2, b1, 4);                                                       \
    if (ST) {                                                                  \
      _Pragma("unroll")                                                        \
      for (int ni_ = 0; ni_ < 4; ++ni_)                                        \
        b1[ni_] = *(const bf16x8*)(Wn + (size_t)ni_ * 16 * D_ + 32);           \
      __builtin_amdgcn_sched_barrier(0);                                       \
    }                                                                          \
  } while (0)

__global__ __launch_bounds__(512, 2) void k_gemm(const u16* __restrict__ X,
                                                 const u16* __restrict__ W,
                                                 u16* __restrict__ C) {
  __shared__ u16 SA[2][2][8192];  // 64 KB: [dbuf][k-half][256 rows x 32 cols]
  int bid = blockIdx.x;
  int swzb = (bid & 7) * 96 + (bid >> 3);   // bijective XCD swizzle (768%8==0)
  int tm = swzb / 12, tn = swzb - tm * 12;
  int m0 = tm << 8, n0 = tn << 8;
  int tid = threadIdx.x;
  int w = tid >> 6, l = tid & 63;
  int wr = w >> 2, wc = w & 3;
  // A staging (R7-proven map: wave-uniform LDS base, pre-swizzled source col)
  int arow = w * 32 + (l >> 2);
  int csw = 8 * ((l & 3) ^ ((l >> 3) & 3));
  const u16* Ag = X + (size_t)(m0 + arow) * D_ + csw;
  int lw = w * 1024;
  // fragment read coords
  int r = l & 15, kq = l >> 4;
  int kcol = 8 * (kq ^ ((r >> 1) & 3));
  // b-frag global source: lane (r,kq), ni: W[n0+wc*64+ni*16+r][kt*64+kh*32+kq*8]
  const u16* Wg = W + (size_t)(n0 + wc * 64 + r) * D_ + kq * 8;

  f32x4 acc[8][4];
  #pragma unroll
  for (int mi = 0; mi < 8; ++mi)
    #pragma unroll
    for (int ni = 0; ni < 4; ++ni)
      #pragma unroll
      for (int q = 0; q < 4; ++q) acc[mi][ni][q] = 0.f;

  bf16x8 af[4], af2[4], b0[4], b1[4];

  // prologue, VMEM order: A-kh0(2), b0(4), A-kh1(2), b1(4)
  GLDS(Ag,      &SA[0][0][lw]);  GLDS(Ag + 16 * D_,      &SA[0][0][lw + 512]);
  __builtin_amdgcn_sched_barrier(0);
  #pragma unroll
  for (int ni = 0; ni < 4; ++ni)
    b0[ni] = *(const bf16x8*)(Wg + (size_t)ni * 16 * D_);
  __builtin_amdgcn_sched_barrier(0);
  GLDS(Ag + 32, &SA[0][1][lw]);  GLDS(Ag + 32 + 16 * D_, &SA[0][1][lw + 512]);
  __builtin_amdgcn_sched_barrier(0);
  #pragma unroll
  for (int ni = 0; ni < 4; ++ni)
    b1[ni] = *(const bf16x8*)(Wg + (size_t)ni * 16 * D_ + 32);
  __builtin_amdgcn_sched_barrier(0);

  for (int kt = 0; kt < NT_ - 1; ++kt) {
    int db = kt & 1, nb = db ^ 1;
    const u16* An = Ag + (size_t)(kt + 1) * 64;
    const u16* Wn = Wg + (size_t)(kt + 1) * 64;
    KTILEB(db, nb, "6", "6", 1);
  }
  {
    const u16* An = Ag;  // unused (ST=0)
    const u16* Wn = Wg;
    KTILEB(1, 0, "6", "0", 0);
  }

  int cr = (l >> 4) * 4, cc = l & 15;
  #pragma unroll
  for (int mi = 0; mi < 8; ++mi)
    #pragma unroll
    for (int ni = 0; ni < 4; ++ni)
      #pragma unroll
      for (int q = 0; q < 4; ++q) {
        int gm = m0 + wr * 128 + mi * 16 + cr + q;
        int gn = n0 + wc * 64 + ni * 16 + cc;
        C[(size_t)gm * NN + gn] = f2b(acc[mi][ni][q]);
      }
}

// K4: fused gk + chunk-sum, 64-t chunks, grid 1024. gk stored f16;
// ct accumulated from the f16-ROUNDED values (bit-consistent with k_decay).
__global__ __launch_bounds__(256) void k_gkcs(const float* __restrict__ y,
                                              const float* __restrict__ w2,
                                              const float* __restrict__ gb,
                                              u16* __restrict__ gkh,
                                              float* __restrict__ ct) {
  __shared__ float yl[64][16];
  int blk = blockIdx.x;
  int cg = blk & 3, tc = (blk >> 2) & 63, b = blk >> 8;
  int tid = threadIdx.x;
  int c = cg * 256 + tid;
  {
    int row = tid >> 2, q = tid & 3;
    const float4* src = (const float4*)(y + (size_t)(b * T_ + tc * 64 + row) * 16 + q * 4);
    *(float4*)&yl[row][q * 4] = *src;
  }
  float w2r[16];
  {
    const float4* wsrc = (const float4*)(w2 + (size_t)c * 16);
    float4 q0 = wsrc[0], q1 = wsrc[1], q2 = wsrc[2], q3 = wsrc[3];
    w2r[0] = q0.x; w2r[1] = q0.y; w2r[2] = q0.z; w2r[3] = q0.w;
    w2r[4] = q1.x; w2r[5] = q1.y; w2r[6] = q1.z; w2r[7] = q1.w;
    w2r[8] = q2.x; w2r[9] = q2.y; w2r[10] = q2.z; w2r[11] = q2.w;
    w2r[12] = q3.x; w2r[13] = q3.y; w2r[14] = q3.z; w2r[15] = q3.w;
  }
  float gbr = gb[c];
  __syncthreads();
  float sum = 0.f;
  size_t rowbase = (size_t)(b * T_ + tc * 64) * HDK + c;
  for (int t = 0; t < 64; ++t) {
    const float4* yv4 = (const float4*)&yl[t][0];
    float4 y0 = yv4[0], y1 = yv4[1], y2 = yv4[2], y3 = yv4[3];
    float z = gbr;
    z = fmaf(y0.x, w2r[0], z);  z = fmaf(y0.y, w2r[1], z);
    z = fmaf(y0.z, w2r[2], z);  z = fmaf(y0.w, w2r[3], z);
    z = fmaf(y1.x, w2r[4], z);  z = fmaf(y1.y, w2r[5], z);
    z = fmaf(y1.z, w2r[6], z);  z = fmaf(y1.w, w2r[7], z);
    z = fmaf(y2.x, w2r[8], z);  z = fmaf(y2.y, w2r[9], z);
    z = fmaf(y2.z, w2r[10], z); z = fmaf(y2.w, w2r[11], z);
    z = fmaf(y3.x, w2r[12], z); z = fmaf(y3.y, w2r[13], z);
    z = fmaf(y3.z, w2r[14], z); z = fmaf(y3.w, w2r[15], z);
    float g = flogsig(z) * (1.f / 16.f);
    _Float16 hv = (_Float16)g;
    u16 bits; __builtin_memcpy(&bits, &hv, 2);
    gkh[rowbase + (size_t)t * HDK] = bits;
    sum += (float)hv;
  }
  ct[(size_t)(b * 64 + tc) * HDK + c] = sum;
}

// E2: scan 64 chunk sums -> exclusive offsets + totals. grid 16 (b x cg).
__global__ __launch_bounds__(256) void k_scan(const float* __restrict__ ct,
                                              float* __restrict__ co,
                                              float* __restrict__ gt) {
  int b = blockIdx.x >> 2, cg = blockIdx.x & 3;
  int c = cg * 256 + threadIdx.x;
  float run = 0.f;
  #pragma unroll 8
  for (int tc = 0; tc < 64; ++tc) {
    size_t idx = (size_t)(b * 64 + tc) * HDK + c;
    co[idx] = run;
    run += ct[idx];
  }
  gt[b * HDK + c] = run;
}

// E3: A = k * exp(g_total - G) (bf16). 64-t chunks, grid 1024.
__global__ __launch_bounds__(256) void k_decay(const u16* __restrict__ gkh,
                                               const float* __restrict__ co,
                                               const float* __restrict__ gt,
                                               const u16* __restrict__ kv,
                                               u16* __restrict__ Ab) {
  int blk = blockIdx.x;
  int cg = blk & 3, tc = (blk >> 2) & 63, b = blk >> 8;
  int c = cg * 256 + threadIdx.x;
  float run = co[(size_t)(b * 64 + tc) * HDK + c];
  float g = gt[b * HDK + c];
  #pragma unroll 8
  for (int tt = 0; tt < 64; ++tt) {
    size_t row = (size_t)(b * T_) + tc * 64 + tt;
    u16 bits = gkh[row * HDK + c];
    _Float16 hv; __builtin_memcpy(&hv, &bits, 2);
    run += (float)hv;
    float decay = fexp(g - run);
    float kvl = b2f(kv[row * NN + c]);
    Ab[row * HDK + c] = f2b(kvl * decay);
  }
}

// K6: MFMA outer product. block = (s, h, b); 8 splits x 512 t; K-steps of 32 t.
__global__ __launch_bounds__(256) void k_outer(const u16* __restrict__ Ab,
                                               const u16* __restrict__ kv,
                                               float* __restrict__ part) {
  __shared__ u16 At[2][64][40];
  __shared__ u16 Vt[2][128][40];
  int s = blockIdx.x, h = blockIdx.y, b = blockIdx.z;
  int tid = threadIdx.x;
  int w = tid >> 6, l = tid & 63;
  int adk = tid & 63, atq = tid >> 6;
  int vdv = tid & 127, vth = tid >> 7;
  int r = l & 15, q = l >> 4;
  f32x4 acc[8];
  #pragma unroll
  for (int n = 0; n < 8; ++n)
    #pragma unroll
    for (int j = 0; j < 4; ++j) acc[n][j] = 0.f;

  union { int4 v[2]; u16 u[16]; } vbuf;
  union { int4 v; u16 u[8]; } abuf;

  #define LOADT(KK) do {                                                              \
      int t0_ = s * 512 + (KK) * 32;                                                  \
      _Pragma("unroll")                                                               \
      for (int i = 0; i < 8; ++i)                                                     \
        abuf.u[i] = Ab[(size_t)(b * T_ + t0_ + atq * 8 + i) * HDK + h * DK_ + adk];   \
      _Pragma("unroll")                                                               \
      for (int i = 0; i < 16; ++i)                                                    \
        vbuf.u[i] = kv[(size_t)(b * T_ + t0_ + vth * 16 + i) * NN + HDK + h * DV_ + vdv]; \
    } while (0)

  #define WRITET(BF) do {                                                             \
      *(int4*)&At[BF][adk][atq * 8] = abuf.v;                                         \
      *(int4*)&Vt[BF][vdv][vth * 16] = vbuf.v[0];                                     \
      *(int4*)&Vt[BF][vdv][vth * 16 + 8] = vbuf.v[1];                                 \
    } while (0)

  LOADT(0);
  WRITET(0);
  for (int kk = 0; kk < 16; ++kk) {
    int cur = kk & 1;
    if (kk < 15) LOADT(kk + 1);
    __syncthreads();
    bf16x8 af = *(const bf16x8*)&At[cur][w * 16 + r][q * 8];
    #pragma unroll
    for (int n = 0; n < 8; ++n) {
      bf16x8 vf = *(const bf16x8*)&Vt[cur][n * 16 + r][q * 8];
      acc[n] = __builtin_amdgcn_mfma_f32_16x16x32_bf16(af, vf, acc[n], 0, 0, 0);
    }
    __syncthreads();
    if (kk < 15) WRITET(1 - cur);
  }
  #undef LOADT
  #undef WRITET

  float* dst = part + ((size_t)(b * H_ + h) * 8 + s) * (DK_ * DV_);
  #pragma unroll
  for (int n = 0; n < 8; ++n)
    #pragma unroll
    for (int j = 0; j < 4; ++j)
      dst[(w * 16 + q * 4 + j) * DV_ + n * 16 + r] = acc[n][j];
}

// K7: out = exp(g_total)*state + sum over 8 splits
__global__ __launch_bounds__(256) void k_final(const float* __restrict__ part,
                                               const float* __restrict__ gt,
                                               const float* __restrict__ st,
                                               float* __restrict__ out) {
  int i = blockIdx.x * 256 + threadIdx.x;
  int dv = i & 127, dk = (i >> 7) & 63, h = (i >> 13) & 15, b = i >> 17;
  size_t base = ((size_t)(b * H_ + h) * 8) * 8192 + dk * DV_ + dv;
  float s = 0.f;
  #pragma unroll
  for (int sp = 0; sp < 8; ++sp) s += part[base + (size_t)sp * 8192];
  float g = gt[b * HDK + h * DK_ + dk];
  out[i] = fexp(g) * st[i] + s;
}

extern "C" void kernel_launch(void* const* d_in, const int* in_sizes, int n_in,
                              void* d_out, int out_size, void* d_ws, size_t ws_size,
                              hipStream_t stream) {
  const float* hs = (const float*)d_in[0];
  const float* st = (const float*)d_in[1];
  const float* nw = (const float*)d_in[2];
  const float* kw = (const float*)d_in[3];
  const float* vw = (const float*)d_in[4];
  const float* w1 = (const float*)d_in[5];
  const float* w2 = (const float*)d_in[6];
  const float* gb = (const float*)d_in[7];
  float* out = (float*)d_out;
  char* ws = (char*)d_ws;

  u16*  Wb  = (u16*)(ws + 0);              // 12,582,912
  u16*  xb  = (u16*)(ws + 12582912);       // 67,108,864 (dead after gemm)
  float* y  = (float*)(ws + 79691776);     //  1,048,576
  u16*  kv  = (u16*)(ws + 80740352);       // 100,663,296
  u16*  gkh = (u16*)(ws + 181403648);      // 33,554,432 (f16)
  float* ct = (float*)(ws + 214958080);    //  1,048,576
  float* co = (float*)(ws + 216006656);    //  1,048,576
  float* gt = (float*)(ws + 217055232);    //     16,384
  u16*  Ab  = (u16*)(ws + 12582912);              // reuse xb region (33.5 MB)
  float* part = (float*)(ws + 12582912 + 33554432); // 16,777,216

  k_cvtw<<<dim3(3072), dim3(256), 0, stream>>>(kw, vw, Wb);
  k_rms<<<dim3(4096), dim3(256), 0, stream>>>(hs, nw, w1, xb, y);
  k_gemm<<<dim3(768), dim3(512), 0, stream>>>(xb, Wb, kv);
  k_gkcs<<<dim3(1024), dim3(256), 0, stream>>>(y, w2, gb, gkh, ct);
  k_scan<<<dim3(16), dim3(256), 0, stream>>>(ct, co, gt);
  k_decay<<<dim3(1024), dim3(256), 0, stream>>>(gkh, co, gt, kv, Ab);
  k_outer<<<dim3(8, 16, 4), dim3(256), 0, stream>>>(Ab, kv, part);
  k_final<<<dim3(2048), dim3(256), 0, stream>>>(part, gt, st, out);
}

// Round 13
// 381.008 us; speedup vs baseline: 1.1388x; 1.1388x over previous
//
#include <hip/hip_runtime.h>

#define B_ 4
#define T_ 4096
#define D_ 2048
#define H_ 16
#define DK_ 64
#define DV_ 128
#define HDK 1024
#define HDV 2048
#define NN 3072
#define MM 16384
#define NT_ 32  // D_/64 K-tiles (BK=64)

typedef unsigned short u16;
typedef unsigned int u32;
typedef __attribute__((ext_vector_type(8))) short bf16x8;
typedef __attribute__((ext_vector_type(4))) float f32x4;

typedef const __attribute__((address_space(1))) u16 gu16;
typedef __attribute__((address_space(3))) u16 lu16;

__device__ __forceinline__ float b2f(u16 u) {
  u32 x = ((u32)u) << 16; float f; __builtin_memcpy(&f, &x, 4); return f;
}
__device__ __forceinline__ u16 f2b(float f) {
  u32 x; __builtin_memcpy(&x, &f, 4);
  u32 r = x + 0x7FFFu + ((x >> 16) & 1u);
  return (u16)(r >> 16);
}
__device__ __forceinline__ float fexp(float x) { return exp2f(x * 1.44269504f); }
__device__ __forceinline__ float flogsig(float z) {
  float u = exp2f(-fabsf(z) * 1.44269504f);
  float l = log2f(1.f + u) * 0.69314718f;
  return fminf(z, 0.f) - l;
}

// K1: convert [k_w; v_w] (3072 x 2048 f32) -> bf16 in FRAGMENT-ORDERED layout:
// Wt flat index ((nr*64 + k32)*64 + kq*16 + r)*8 + e, where n = nr*16+r,
// k = k32*32 + kq*8 + e. A wave's b-frag load (fixed nr,k32) is then
// lane l -> base + l*16B: one fully coalesced 1KB transaction.
__global__ __launch_bounds__(256) void k_cvtw(const float* __restrict__ kw,
                                              const float* __restrict__ vw,
                                              u16* __restrict__ Wt) {
  int i = blockIdx.x * 256 + threadIdx.x;
  size_t e = (size_t)i * 8;
  const float* src = (e < (size_t)HDK * D_) ? (kw + e) : (vw + (e - (size_t)HDK * D_));
  float4 f0 = ((const float4*)src)[0];
  float4 f1 = ((const float4*)src)[1];
  union { int4 v; u16 u[8]; } o;
  o.u[0] = f2b(f0.x); o.u[1] = f2b(f0.y); o.u[2] = f2b(f0.z); o.u[3] = f2b(f0.w);
  o.u[4] = f2b(f1.x); o.u[5] = f2b(f1.y); o.u[6] = f2b(f1.z); o.u[7] = f2b(f1.w);
  int n = i >> 8;             // row (0..3071)
  int k0 = (i & 255) * 8;     // col of first element
  int nr = n >> 4, r = n & 15;
  int k32 = k0 >> 5, kq = (k0 >> 3) & 3;
  size_t flat = (((size_t)nr * 64 + k32) * 64 + kq * 16 + r) * 8;
  *(int4*)(Wt + flat) = o.v;
}

// K2: RMSNorm -> x (bf16), and y = x @ gk_w1^T (f32, 16 per row). 4 rows/block.
// (R3/R5-proven version.)
__global__ __launch_bounds__(256) void k_rms(const float* __restrict__ hs,
                                             const float* __restrict__ nw,
                                             const float* __restrict__ w1,
                                             u16* __restrict__ xb,
                                             float* __restrict__ y) {
  int r0 = blockIdx.x * 4;
  int tid = threadIdx.x;
  int wv = tid >> 6, ln = tid & 63;
  __shared__ float red[4][4];
  __shared__ float ys[4][4][16];
  float x[4][8];
  float ssq[4];
  #pragma unroll
  for (int r = 0; r < 4; ++r) {
    const float4* hp = (const float4*)(hs + (size_t)(r0 + r) * D_);
    float4 a = hp[tid * 2], b = hp[tid * 2 + 1];
    x[r][0] = a.x; x[r][1] = a.y; x[r][2] = a.z; x[r][3] = a.w;
    x[r][4] = b.x; x[r][5] = b.y; x[r][6] = b.z; x[r][7] = b.w;
    float s = 0.f;
    #pragma unroll
    for (int i = 0; i < 8; ++i) s += x[r][i] * x[r][i];
    #pragma unroll
    for (int o = 32; o > 0; o >>= 1) s += __shfl_xor(s, o, 64);
    ssq[r] = s;
  }
  if (ln == 0) {
    #pragma unroll
    for (int r = 0; r < 4; ++r) red[wv][r] = ssq[r];
  }
  __syncthreads();
  const float4* np_ = (const float4*)nw;
  float4 n0 = np_[tid * 2], n1 = np_[tid * 2 + 1];
  float nwv[8] = {n0.x, n0.y, n0.z, n0.w, n1.x, n1.y, n1.z, n1.w};
  #pragma unroll
  for (int r = 0; r < 4; ++r) {
    float tot = red[0][r] + red[1][r] + red[2][r] + red[3][r];
    float inv = rsqrtf(tot * (1.f / D_) + 1e-5f);
    union { int4 v; u16 u[8]; } o;
    #pragma unroll
    for (int i = 0; i < 8; ++i) { x[r][i] = x[r][i] * inv * nwv[i]; o.u[i] = f2b(x[r][i]); }
    *(int4*)(xb + (size_t)(r0 + r) * D_ + tid * 8) = o.v;
  }
  float p[4][16];
  #pragma unroll
  for (int r = 0; r < 4; ++r)
    #pragma unroll
    for (int j = 0; j < 16; ++j) p[r][j] = 0.f;
  #pragma unroll
  for (int j = 0; j < 16; ++j) {
    const float4* wp = (const float4*)(w1 + (size_t)j * D_);
    float4 a = wp[tid * 2], b = wp[tid * 2 + 1];
    float wj[8] = {a.x, a.y, a.z, a.w, b.x, b.y, b.z, b.w};
    #pragma unroll
    for (int r = 0; r < 4; ++r) {
      float s = 0.f;
      #pragma unroll
      for (int i = 0; i < 8; ++i) s += x[r][i] * wj[i];
      p[r][j] = s;
    }
  }
  #pragma unroll
  for (int r = 0; r < 4; ++r)
    #pragma unroll
    for (int j = 0; j < 16; ++j) {
      float s = p[r][j];
      #pragma unroll
      for (int o = 32; o > 0; o >>= 1) s += __shfl_xor(s, o, 64);
      p[r][j] = s;
    }
  if (ln == 0) {
    for (int r = 0; r < 4; ++r)
      for (int j = 0; j < 16; ++j) ys[wv][r][j] = p[r][j];
  }
  __syncthreads();
  if (tid < 64) {
    int r = tid >> 4, j = tid & 15;
    y[(size_t)(r0 + r) * 16 + j] = ys[0][r][j] + ys[1][r][j] + ys[2][r][j] + ys[3][r][j];
  }
}

// K3: kv = x @ Wt'. 256x256 tile, 8 waves, BK=64. B-operand from global
// (fragment-ordered Wt, fully coalesced); LDS holds A only (64 KB, 2dbuf x 2kh).
// Per-tile VMEM order: [P0: A-kh0(2)] [P1-end: b0(4)] [P2: A-kh1(2)] [P3-end: b1(4)].
// vmcnt(6) at P0/P2 (6 newer ops outstanding); last tile P2 -> vmcnt(0).
#define GLDS(SRC, DST) __builtin_amdgcn_global_load_lds((gu16*)(SRC), (lu16*)(DST), 16, 0, 0)

#define MFMA16B(AF, BB, MB) do {                                               \
    __builtin_amdgcn_s_setprio(1);                                             \
    _Pragma("unroll")                                                          \
    for (int mi_ = 0; mi_ < 4; ++mi_)                                          \
      _Pragma("unroll")                                                        \
      for (int ni_ = 0; ni_ < 4; ++ni_)                                        \
        acc[(MB) + mi_][ni_] = __builtin_amdgcn_mfma_f32_16x16x32_bf16(        \
            AF[mi_], BB[ni_], acc[(MB) + mi_][ni_], 0, 0, 0);                  \
    __builtin_amdgcn_s_setprio(0);                                             \
    __builtin_amdgcn_sched_barrier(0);                                         \
  } while (0)

#define KTILEB(DB, NB, VM0, VM2, ST) do {                                      \
    /* P0: wait, read kh0 a-frags 0-3, stage A-kh0', MFMA (b0) */              \
    asm volatile("s_waitcnt vmcnt(" VM0 ")" ::: "memory");                     \
    __builtin_amdgcn_s_barrier();                                              \
    __builtin_amdgcn_sched_barrier(0);                                         \
    _Pragma("unroll")                                                          \
    for (int mi_ = 0; mi_ < 4; ++mi_)                                          \
      af[mi_] = *(const bf16x8*)&SA[DB][0][(wr * 128 + mi_ * 16 + r) * 32 + kcol]; \
    if (ST) { GLDS(An, &SA[NB][0][lw]); GLDS(An + 16 * D_, &SA[NB][0][lw + 512]); } \
    __builtin_amdgcn_sched_barrier(0);                                         \
    asm volatile("s_waitcnt lgkmcnt(0)" ::: "memory");                         \
    __builtin_amdgcn_sched_barrier(0);                                         \
    MFMA16B(af, b0, 0);                                                        \
    /* P1: read a-frags 4-7 kh0, MFMA (b0), then reload b0 <- next tile kh0 */ \
    _Pragma("unroll")                                                          \
    for (int mi_ = 0; mi_ < 4; ++mi_)                                          \
      af2[mi_] = *(const bf16x8*)&SA[DB][0][(wr * 128 + (4 + mi_) * 16 + r) * 32 + kcol]; \
    asm volatile("s_waitcnt lgkmcnt(0)" ::: "memory");                         \
    __builtin_amdgcn_sched_barrier(0);                                         \
    MFMA16B(af2, b0, 4);                                                       \
    if (ST) {                                                                  \
      _Pragma("unroll")                                                        \
      for (int ni_ = 0; ni_ < 4; ++ni_)                                        \
        b0[ni_] = *(const bf16x8*)(Wn + (size_t)ni_ * 32768);                  \
      __builtin_amdgcn_sched_barrier(0);                                       \
    }                                                                          \
    /* P2: wait, read kh1 a-frags 0-3, stage A-kh1', MFMA (b1) */              \
    asm volatile("s_waitcnt vmcnt(" VM2 ")" ::: "memory");                     \
    __builtin_amdgcn_s_barrier();                                              \
    __builtin_amdgcn_sched_barrier(0);                                         \
    _Pragma("unroll")                                                          \
    for (int mi_ = 0; mi_ < 4; ++mi_)                                          \
      af[mi_] = *(const bf16x8*)&SA[DB][1][(wr * 128 + mi_ * 16 + r) * 32 + kcol]; \
    if (ST) { GLDS(An + 32, &SA[NB][1][lw]); GLDS(An + 32 + 16 * D_, &SA[NB][1][lw + 512]); } \
    __builtin_amdgcn_sched_barrier(0);                                         \
    asm volatile("s_waitcnt lgkmcnt(0)" ::: "memory");                         \
    __builtin_amdgcn_sched_barrier(0);                                         \
    MFMA16B(af, b1, 0);                                                        \
    /* P3: read a-frags 4-7 kh1, MFMA (b1), then reload b1 <- next tile kh1 */ \
    _Pragma("unroll")                                                          \
    for (int mi_ = 0; mi_ < 4; ++mi_)                                          \
      af2[mi_] = *(const bf16x8*)&SA[DB][1][(wr * 128 + (4 + mi_) * 16 + r) * 32 + kcol]; \
    asm volatile("s_waitcnt lgkmcnt(0)" ::: "memory");                         \
    __builtin_amdgcn_sched_barrier(0);                                         \
    MFMA16B(af2, b1, 4);                                                       \
    if (ST) {                                                                  \
      _Pragma("unroll")                                                        \
      for (int ni_ = 0; ni_ < 4; ++ni_)                                        \
        b1[ni_] = *(const bf16x8*)(Wn + (size_t)ni_ * 32768 + 512);            \
      __builtin_amdgcn_sched_barrier(0);                                       \
    }                                                                          \
  } while (0)

__global__ __launch_bounds__(512, 2) void k_gemm(const u16* __restrict__ X,
                                                 const u16* __restrict__ Wt,
                                                 u16* __restrict__ C) {
  __shared__ u16 SA[2][2][8192];  // 64 KB: [dbuf][k-half][256 rows x 32 cols]
  int bid = blockIdx.x;
  int swzb = (bid & 7) * 96 + (bid >> 3);   // bijective XCD swizzle (768%8==0)
  int tm = swzb / 12, tn = swzb - tm * 12;
  int m0 = tm << 8, n0 = tn << 8;
  int tid = threadIdx.x;
  int w = tid >> 6, l = tid & 63;
  int wr = w >> 2, wc = w & 3;
  // A staging (R7-proven map: wave-uniform LDS base, pre-swizzled source col)
  int arow = w * 32 + (l >> 2);
  int csw = 8 * ((l & 3) ^ ((l >> 3) & 3));
  const u16* Ag = X + (size_t)(m0 + arow) * D_ + csw;
  int lw = w * 1024;
  // fragment read coords
  int r = l & 15, kq = l >> 4;
  int kcol = 8 * (kq ^ ((r >> 1) & 3));
  // b-frag source in fragment-ordered Wt: block (nr0+wc*4+ni), k32=kt*2+kh,
  // lane l at +l*8. Per-(ni) stride 32768 u16; per-k32 stride 512 u16.
  const u16* Wp = Wt + ((size_t)(tn * 16 + wc * 4) * 64 + 0) * 512 + (size_t)l * 8;

  f32x4 acc[8][4];
  #pragma unroll
  for (int mi = 0; mi < 8; ++mi)
    #pragma unroll
    for (int ni = 0; ni < 4; ++ni)
      #pragma unroll
      for (int q = 0; q < 4; ++q) acc[mi][ni][q] = 0.f;

  bf16x8 af[4], af2[4], b0[4], b1[4];

  // prologue, VMEM order: A-kh0(2), b0(4), A-kh1(2), b1(4)
  GLDS(Ag,      &SA[0][0][lw]);  GLDS(Ag + 16 * D_,      &SA[0][0][lw + 512]);
  __builtin_amdgcn_sched_barrier(0);
  #pragma unroll
  for (int ni = 0; ni < 4; ++ni)
    b0[ni] = *(const bf16x8*)(Wp + (size_t)ni * 32768);
  __builtin_amdgcn_sched_barrier(0);
  GLDS(Ag + 32, &SA[0][1][lw]);  GLDS(Ag + 32 + 16 * D_, &SA[0][1][lw + 512]);
  __builtin_amdgcn_sched_barrier(0);
  #pragma unroll
  for (int ni = 0; ni < 4; ++ni)
    b1[ni] = *(const bf16x8*)(Wp + (size_t)ni * 32768 + 512);
  __builtin_amdgcn_sched_barrier(0);

  for (int kt = 0; kt < NT_ - 1; ++kt) {
    int db = kt & 1, nb = db ^ 1;
    const u16* An = Ag + (size_t)(kt + 1) * 64;
    const u16* Wn = Wp + (size_t)(kt + 1) * 1024;  // (kt+1)*2 k32-steps * 512
    KTILEB(db, nb, "6", "6", 1);
  }
  {
    const u16* An = Ag;  // unused (ST=0)
    const u16* Wn = Wp;
    KTILEB(1, 0, "6", "0", 0);
  }

  int cr = (l >> 4) * 4, cc = l & 15;
  #pragma unroll
  for (int mi = 0; mi < 8; ++mi)
    #pragma unroll
    for (int ni = 0; ni < 4; ++ni)
      #pragma unroll
      for (int q = 0; q < 4; ++q) {
        int gm = m0 + wr * 128 + mi * 16 + cr + q;
        int gn = n0 + wc * 64 + ni * 16 + cc;
        C[(size_t)gm * NN + gn] = f2b(acc[mi][ni][q]);
      }
}

// K4: fused gk + chunk-sum, 64-t chunks, grid 1024. gk stored f16;
// ct accumulated from the f16-ROUNDED values (bit-consistent with k_decay).
__global__ __launch_bounds__(256) void k_gkcs(const float* __restrict__ y,
                                              const float* __restrict__ w2,
                                              const float* __restrict__ gb,
                                              u16* __restrict__ gkh,
                                              float* __restrict__ ct) {
  __shared__ float yl[64][16];
  int blk = blockIdx.x;
  int cg = blk & 3, tc = (blk >> 2) & 63, b = blk >> 8;
  int tid = threadIdx.x;
  int c = cg * 256 + tid;
  {
    int row = tid >> 2, q = tid & 3;
    const float4* src = (const float4*)(y + (size_t)(b * T_ + tc * 64 + row) * 16 + q * 4);
    *(float4*)&yl[row][q * 4] = *src;
  }
  float w2r[16];
  {
    const float4* wsrc = (const float4*)(w2 + (size_t)c * 16);
    float4 q0 = wsrc[0], q1 = wsrc[1], q2 = wsrc[2], q3 = wsrc[3];
    w2r[0] = q0.x; w2r[1] = q0.y; w2r[2] = q0.z; w2r[3] = q0.w;
    w2r[4] = q1.x; w2r[5] = q1.y; w2r[6] = q1.z; w2r[7] = q1.w;
    w2r[8] = q2.x; w2r[9] = q2.y; w2r[10] = q2.z; w2r[11] = q2.w;
    w2r[12] = q3.x; w2r[13] = q3.y; w2r[14] = q3.z; w2r[15] = q3.w;
  }
  float gbr = gb[c];
  __syncthreads();
  float sum = 0.f;
  size_t rowbase = (size_t)(b * T_ + tc * 64) * HDK + c;
  for (int t = 0; t < 64; ++t) {
    const float4* yv4 = (const float4*)&yl[t][0];
    float4 y0 = yv4[0], y1 = yv4[1], y2 = yv4[2], y3 = yv4[3];
    float z = gbr;
    z = fmaf(y0.x, w2r[0], z);  z = fmaf(y0.y, w2r[1], z);
    z = fmaf(y0.z, w2r[2], z);  z = fmaf(y0.w, w2r[3], z);
    z = fmaf(y1.x, w2r[4], z);  z = fmaf(y1.y, w2r[5], z);
    z = fmaf(y1.z, w2r[6], z);  z = fmaf(y1.w, w2r[7], z);
    z = fmaf(y2.x, w2r[8], z);  z = fmaf(y2.y, w2r[9], z);
    z = fmaf(y2.z, w2r[10], z); z = fmaf(y2.w, w2r[11], z);
    z = fmaf(y3.x, w2r[12], z); z = fmaf(y3.y, w2r[13], z);
    z = fmaf(y3.z, w2r[14], z); z = fmaf(y3.w, w2r[15], z);
    float g = flogsig(z) * (1.f / 16.f);
    _Float16 hv = (_Float16)g;
    u16 bits; __builtin_memcpy(&bits, &hv, 2);
    gkh[rowbase + (size_t)t * HDK] = bits;
    sum += (float)hv;
  }
  ct[(size_t)(b * 64 + tc) * HDK + c] = sum;
}

// E2: scan 64 chunk sums -> exclusive offsets + totals. grid 16 (b x cg).
__global__ __launch_bounds__(256) void k_scan(const float* __restrict__ ct,
                                              float* __restrict__ co,
                                              float* __restrict__ gt) {
  int b = blockIdx.x >> 2, cg = blockIdx.x & 3;
  int c = cg * 256 + threadIdx.x;
  float run = 0.f;
  #pragma unroll 8
  for (int tc = 0; tc < 64; ++tc) {
    size_t idx = (size_t)(b * 64 + tc) * HDK + c;
    co[idx] = run;
    run += ct[idx];
  }
  gt[b * HDK + c] = run;
}

// E3: A = k * exp(g_total - G) (bf16). 64-t chunks, grid 1024.
__global__ __launch_bounds__(256) void k_decay(const u16* __restrict__ gkh,
                                               const float* __restrict__ co,
                                               const float* __restrict__ gt,
                                               const u16* __restrict__ kv,
                                               u16* __restrict__ Ab) {
  int blk = blockIdx.x;
  int cg = blk & 3, tc = (blk >> 2) & 63, b = blk >> 8;
  int c = cg * 256 + threadIdx.x;
  float run = co[(size_t)(b * 64 + tc) * HDK + c];
  float g = gt[b * HDK + c];
  #pragma unroll 8
  for (int tt = 0; tt < 64; ++tt) {
    size_t row = (size_t)(b * T_) + tc * 64 + tt;
    u16 bits = gkh[row * HDK + c];
    _Float16 hv; __builtin_memcpy(&hv, &bits, 2);
    run += (float)hv;
    float decay = fexp(g - run);
    float kvl = b2f(kv[row * NN + c]);
    Ab[row * HDK + c] = f2b(kvl * decay);
  }
}

// K6: MFMA outer product. block = (s, h, b); 8 splits x 512 t; K-steps of 32 t.
__global__ __launch_bounds__(256) void k_outer(const u16* __restrict__ Ab,
                                               const u16* __restrict__ kv,
                                               float* __restrict__ part) {
  __shared__ u16 At[2][64][40];
  __shared__ u16 Vt[2][128][40];
  int s = blockIdx.x, h = blockIdx.y, b = blockIdx.z;
  int tid = threadIdx.x;
  int w = tid >> 6, l = tid & 63;
  int adk = tid & 63, atq = tid >> 6;
  int vdv = tid & 127, vth = tid >> 7;
  int r = l & 15, q = l >> 4;
  f32x4 acc[8];
  #pragma unroll
  for (int n = 0; n < 8; ++n)
    #pragma unroll
    for (int j = 0; j < 4; ++j) acc[n][j] = 0.f;

  union { int4 v[2]; u16 u[16]; } vbuf;
  union { int4 v; u16 u[8]; } abuf;

  #define LOADT(KK) do {                                                              \
      int t0_ = s * 512 + (KK) * 32;                                                  \
      _Pragma("unroll")                                                               \
      for (int i = 0; i < 8; ++i)                                                     \
        abuf.u[i] = Ab[(size_t)(b * T_ + t0_ + atq * 8 + i) * HDK + h * DK_ + adk];   \
      _Pragma("unroll")                                                               \
      for (int i = 0; i < 16; ++i)                                                    \
        vbuf.u[i] = kv[(size_t)(b * T_ + t0_ + vth * 16 + i) * NN + HDK + h * DV_ + vdv]; \
    } while (0)

  #define WRITET(BF) do {                                                             \
      *(int4*)&At[BF][adk][atq * 8] = abuf.v;                                         \
      *(int4*)&Vt[BF][vdv][vth * 16] = vbuf.v[0];                                     \
      *(int4*)&Vt[BF][vdv][vth * 16 + 8] = vbuf.v[1];                                 \
    } while (0)

  LOADT(0);
  WRITET(0);
  for (int kk = 0; kk < 16; ++kk) {
    int cur = kk & 1;
    if (kk < 15) LOADT(kk + 1);
    __syncthreads();
    bf16x8 af = *(const bf16x8*)&At[cur][w * 16 + r][q * 8];
    #pragma unroll
    for (int n = 0; n < 8; ++n) {
      bf16x8 vf = *(const bf16x8*)&Vt[cur][n * 16 + r][q * 8];
      acc[n] = __builtin_amdgcn_mfma_f32_16x16x32_bf16(af, vf, acc[n], 0, 0, 0);
    }
    __syncthreads();
    if (kk < 15) WRITET(1 - cur);
  }
  #undef LOADT
  #undef WRITET

  float* dst = part + ((size_t)(b * H_ + h) * 8 + s) * (DK_ * DV_);
  #pragma unroll
  for (int n = 0; n < 8; ++n)
    #pragma unroll
    for (int j = 0; j < 4; ++j)
      dst[(w * 16 + q * 4 + j) * DV_ + n * 16 + r] = acc[n][j];
}

// K7: out = exp(g_total)*state + sum over 8 splits
__global__ __launch_bounds__(256) void k_final(const float* __restrict__ part,
                                               const float* __restrict__ gt,
                                               const float* __restrict__ st,
                                               float* __restrict__ out) {
  int i = blockIdx.x * 256 + threadIdx.x;
  int dv = i & 127, dk = (i >> 7) & 63, h = (i >> 13) & 15, b = i >> 17;
  size_t base = ((size_t)(b * H_ + h) * 8) * 8192 + dk * DV_ + dv;
  float s = 0.f;
  #pragma unroll
  for (int sp = 0; sp < 8; ++sp) s += part[base + (size_t)sp * 8192];
  float g = gt[b * HDK + h * DK_ + dk];
  out[i] = fexp(g) * st[i] + s;
}

extern "C" void kernel_launch(void* const* d_in, const int* in_sizes, int n_in,
                              void* d_out, int out_size, void* d_ws, size_t ws_size,
                              hipStream_t stream) {
  const float* hs = (const float*)d_in[0];
  const float* st = (const float*)d_in[1];
  const float* nw = (const float*)d_in[2];
  const float* kw = (const float*)d_in[3];
  const float* vw = (const float*)d_in[4];
  const float* w1 = (const float*)d_in[5];
  const float* w2 = (const float*)d_in[6];
  const float* gb = (const float*)d_in[7];
  float* out = (float*)d_out;
  char* ws = (char*)d_ws;

  u16*  Wt  = (u16*)(ws + 0);              // 12,582,912 (fragment-ordered)
  u16*  xb  = (u16*)(ws + 12582912);       // 67,108,864 (dead after gemm)
  float* y  = (float*)(ws + 79691776);     //  1,048,576
  u16*  kv  = (u16*)(ws + 80740352);       // 100,663,296
  u16*  gkh = (u16*)(ws + 181403648);      // 33,554,432 (f16)
  float* ct = (float*)(ws + 214958080);    //  1,048,576
  float* co = (float*)(ws + 216006656);    //  1,048,576
  float* gt = (float*)(ws + 217055232);    //     16,384
  u16*  Ab  = (u16*)(ws + 12582912);              // reuse xb region (33.5 MB)
  float* part = (float*)(ws + 12582912 + 33554432); // 16,777,216

  k_cvtw<<<dim3(3072), dim3(256), 0, stream>>>(kw, vw, Wt);
  k_rms<<<dim3(4096), dim3(256), 0, stream>>>(hs, nw, w1, xb, y);
  k_gemm<<<dim3(768), dim3(512), 0, stream>>>(xb, Wt, kv);
  k_gkcs<<<dim3(1024), dim3(256), 0, stream>>>(y, w2, gb, gkh, ct);
  k_scan<<<dim3(16), dim3(256), 0, stream>>>(ct, co, gt);
  k_decay<<<dim3(1024), dim3(256), 0, stream>>>(gkh, co, gt, kv, Ab);
  k_outer<<<dim3(8, 16, 4), dim3(256), 0, stream>>>(Ab, kv, part);
  k_final<<<dim3(2048), dim3(256), 0, stream>>>(part, gt, st, out);
}

// Round 14
// 377.029 us; speedup vs baseline: 1.1508x; 1.0106x over previous
//
#include <hip/hip_runtime.h>

#define B_ 4
#define T_ 4096
#define D_ 2048
#define H_ 16
#define DK_ 64
#define DV_ 128
#define HDK 1024
#define HDV 2048
#define NN 3072
#define MM 16384
#define NT_ 32  // D_/64 K-tiles (BK=64)

typedef unsigned short u16;
typedef unsigned int u32;
typedef __attribute__((ext_vector_type(8))) short bf16x8;
typedef __attribute__((ext_vector_type(4))) float f32x4;
typedef __attribute__((ext_vector_type(16))) float f32x16;

typedef const __attribute__((address_space(1))) u16 gu16;
typedef __attribute__((address_space(3))) u16 lu16;

__device__ __forceinline__ float b2f(u16 u) {
  u32 x = ((u32)u) << 16; float f; __builtin_memcpy(&f, &x, 4); return f;
}
__device__ __forceinline__ u16 f2b(float f) {
  u32 x; __builtin_memcpy(&x, &f, 4);
  u32 r = x + 0x7FFFu + ((x >> 16) & 1u);
  return (u16)(r >> 16);
}
__device__ __forceinline__ float fexp(float x) { return exp2f(x * 1.44269504f); }
__device__ __forceinline__ float flogsig(float z) {
  float u = exp2f(-fabsf(z) * 1.44269504f);
  float l = log2f(1.f + u) * 0.69314718f;
  return fminf(z, 0.f) - l;
}

// K1: convert [k_w; v_w] (3072 x 2048 f32) -> bf16 (row-major, R11 layout)
__global__ __launch_bounds__(256) void k_cvtw(const float* __restrict__ kw,
                                              const float* __restrict__ vw,
                                              u16* __restrict__ Wb) {
  int i = blockIdx.x * 256 + threadIdx.x;
  size_t e = (size_t)i * 8;
  const float* src = (e < (size_t)HDK * D_) ? (kw + e) : (vw + (e - (size_t)HDK * D_));
  float4 f0 = ((const float4*)src)[0];
  float4 f1 = ((const float4*)src)[1];
  union { int4 v; u16 u[8]; } o;
  o.u[0] = f2b(f0.x); o.u[1] = f2b(f0.y); o.u[2] = f2b(f0.z); o.u[3] = f2b(f0.w);
  o.u[4] = f2b(f1.x); o.u[5] = f2b(f1.y); o.u[6] = f2b(f1.z); o.u[7] = f2b(f1.w);
  *(int4*)(Wb + e) = o.v;
}

// K2: RMSNorm -> x (bf16), and y = x @ gk_w1^T (f32, 16 per row). 4 rows/block.
// (R3/R5-proven version.)
__global__ __launch_bounds__(256) void k_rms(const float* __restrict__ hs,
                                             const float* __restrict__ nw,
                                             const float* __restrict__ w1,
                                             u16* __restrict__ xb,
                                             float* __restrict__ y) {
  int r0 = blockIdx.x * 4;
  int tid = threadIdx.x;
  int wv = tid >> 6, ln = tid & 63;
  __shared__ float red[4][4];
  __shared__ float ys[4][4][16];
  float x[4][8];
  float ssq[4];
  #pragma unroll
  for (int r = 0; r < 4; ++r) {
    const float4* hp = (const float4*)(hs + (size_t)(r0 + r) * D_);
    float4 a = hp[tid * 2], b = hp[tid * 2 + 1];
    x[r][0] = a.x; x[r][1] = a.y; x[r][2] = a.z; x[r][3] = a.w;
    x[r][4] = b.x; x[r][5] = b.y; x[r][6] = b.z; x[r][7] = b.w;
    float s = 0.f;
    #pragma unroll
    for (int i = 0; i < 8; ++i) s += x[r][i] * x[r][i];
    #pragma unroll
    for (int o = 32; o > 0; o >>= 1) s += __shfl_xor(s, o, 64);
    ssq[r] = s;
  }
  if (ln == 0) {
    #pragma unroll
    for (int r = 0; r < 4; ++r) red[wv][r] = ssq[r];
  }
  __syncthreads();
  const float4* np_ = (const float4*)nw;
  float4 n0 = np_[tid * 2], n1 = np_[tid * 2 + 1];
  float nwv[8] = {n0.x, n0.y, n0.z, n0.w, n1.x, n1.y, n1.z, n1.w};
  #pragma unroll
  for (int r = 0; r < 4; ++r) {
    float tot = red[0][r] + red[1][r] + red[2][r] + red[3][r];
    float inv = rsqrtf(tot * (1.f / D_) + 1e-5f);
    union { int4 v; u16 u[8]; } o;
    #pragma unroll
    for (int i = 0; i < 8; ++i) { x[r][i] = x[r][i] * inv * nwv[i]; o.u[i] = f2b(x[r][i]); }
    *(int4*)(xb + (size_t)(r0 + r) * D_ + tid * 8) = o.v;
  }
  float p[4][16];
  #pragma unroll
  for (int r = 0; r < 4; ++r)
    #pragma unroll
    for (int j = 0; j < 16; ++j) p[r][j] = 0.f;
  #pragma unroll
  for (int j = 0; j < 16; ++j) {
    const float4* wp = (const float4*)(w1 + (size_t)j * D_);
    float4 a = wp[tid * 2], b = wp[tid * 2 + 1];
    float wj[8] = {a.x, a.y, a.z, a.w, b.x, b.y, b.z, b.w};
    #pragma unroll
    for (int r = 0; r < 4; ++r) {
      float s = 0.f;
      #pragma unroll
      for (int i = 0; i < 8; ++i) s += x[r][i] * wj[i];
      p[r][j] = s;
    }
  }
  #pragma unroll
  for (int r = 0; r < 4; ++r)
    #pragma unroll
    for (int j = 0; j < 16; ++j) {
      float s = p[r][j];
      #pragma unroll
      for (int o = 32; o > 0; o >>= 1) s += __shfl_xor(s, o, 64);
      p[r][j] = s;
    }
  if (ln == 0) {
    for (int r = 0; r < 4; ++r)
      for (int j = 0; j < 16; ++j) ys[wv][r][j] = p[r][j];
  }
  __syncthreads();
  if (tid < 64) {
    int r = tid >> 4, j = tid & 15;
    y[(size_t)(r0 + r) * 16 + j] = ys[0][r][j] + ys[1][r][j] + ys[2][r][j] + ys[3][r][j];
  }
}

// K3: kv = x @ Wb^T. 256x256 tile, 8 waves, BK=64, 2 dbuf x 2 k-half LDS,
// R7/R11-proven staging (wave-uniform GLDS dest, pre-swizzled source cols).
// NEW (R14): 32x32x16 MFMA (2495 TF ceiling vs 2176; half the issue slots).
// Wave output 128x64 = 4m x 2n tiles of 32x32. 2 phases per K-tile (kh0/kh1),
// 16 MFMA each; vmcnt(4) steady state (other phase's 4 stages outstanding).
#define GLDS(SRC, DST) __builtin_amdgcn_global_load_lds((gu16*)(SRC), (lu16*)(DST), 16, 0, 0)

// A-frag addr: row ra = wr*128+mt*32+(l&31), col 8*((ks*2+(l>>5))^phi(ra))
// B-frag addr: row rb = wc*64 +nt*32+(l&31), col 8*((ks*2+(l>>5))^phi(rb))
#define PHASE32(DB, KH, VMSTR, DO_ST, STBASE) do {                             \
    asm volatile("s_waitcnt vmcnt(" VMSTR ")" ::: "memory");                   \
    __builtin_amdgcn_s_barrier();                                              \
    __builtin_amdgcn_sched_barrier(0);                                         \
    bf16x8 a_[4][2], b_[2][2];                                                 \
    _Pragma("unroll")                                                          \
    for (int mt = 0; mt < 4; ++mt)                                             \
      _Pragma("unroll")                                                        \
      for (int ks = 0; ks < 2; ++ks) {                                         \
        int ra = wr * 128 + mt * 32 + l31;                                     \
        int col = 8 * (((ks << 1) | lh) ^ ((ra >> 1) & 3));                    \
        a_[mt][ks] = *(const bf16x8*)&SA[DB][KH][ra * 32 + col];               \
      }                                                                        \
    _Pragma("unroll")                                                          \
    for (int nt = 0; nt < 2; ++nt)                                             \
      _Pragma("unroll")                                                        \
      for (int ks = 0; ks < 2; ++ks) {                                         \
        int rb = wc * 64 + nt * 32 + l31;                                      \
        int col = 8 * (((ks << 1) | lh) ^ ((rb >> 1) & 3));                    \
        b_[nt][ks] = *(const bf16x8*)&SB[DB][KH][rb * 32 + col];               \
      }                                                                        \
    if (DO_ST) {                                                               \
      GLDS((STBASE) + (KH) * 32,            &SA[DB ^ 1][KH][lw]);              \
      GLDS((STBASE) + (KH) * 32 + 16 * D_,  &SA[DB ^ 1][KH][lw + 512]);        \
      GLDS((STBASE##B) + (KH) * 32,           &SB[DB ^ 1][KH][lw]);            \
      GLDS((STBASE##B) + (KH) * 32 + 16 * D_, &SB[DB ^ 1][KH][lw + 512]);      \
    }                                                                          \
    asm volatile("s_waitcnt lgkmcnt(0)" ::: "memory");                         \
    __builtin_amdgcn_sched_barrier(0);                                         \
    __builtin_amdgcn_s_setprio(1);                                             \
    _Pragma("unroll")                                                          \
    for (int ks = 0; ks < 2; ++ks)                                             \
      _Pragma("unroll")                                                        \
      for (int mt = 0; mt < 4; ++mt)                                           \
        _Pragma("unroll")                                                      \
        for (int nt = 0; nt < 2; ++nt)                                         \
          acc[mt][nt] = __builtin_amdgcn_mfma_f32_32x32x16_bf16(               \
              a_[mt][ks], b_[nt][ks], acc[mt][nt], 0, 0, 0);                   \
    __builtin_amdgcn_s_setprio(0);                                             \
    __builtin_amdgcn_sched_barrier(0);                                         \
  } while (0)

__global__ __launch_bounds__(512, 2) void k_gemm(const u16* __restrict__ X,
                                                 const u16* __restrict__ W,
                                                 u16* __restrict__ C) {
  __shared__ u16 SA[2][2][8192];  // [dbuf][k-half][256 rows x 32 cols]
  __shared__ u16 SB[2][2][8192];
  int bid = blockIdx.x;
  int swzb = (bid & 7) * 96 + (bid >> 3);   // bijective XCD swizzle (768%8==0)
  int tm = swzb / 12, tn = swzb - tm * 12;
  int m0 = tm << 8, n0 = tn << 8;
  int tid = threadIdx.x;
  int w = tid >> 6, l = tid & 63;
  int wr = w >> 2, wc = w & 3;
  int l31 = l & 31, lh = l >> 5;
  // staging coords (wave-uniform LDS base; per-lane global src) — R7-proven
  int arow = w * 32 + (l >> 2);
  int csw = 8 * ((l & 3) ^ ((l >> 3) & 3));
  const u16* Ag = X + (size_t)(m0 + arow) * D_ + csw;
  const u16* Bg = W + (size_t)(n0 + arow) * D_ + csw;
  int lw = w * 1024;

  f32x16 acc[4][2];
  #pragma unroll
  for (int mt = 0; mt < 4; ++mt)
    #pragma unroll
    for (int nt = 0; nt < 2; ++nt)
      #pragma unroll
      for (int q = 0; q < 16; ++q) acc[mt][nt][q] = 0.f;

  // prologue: tile 0 in FIFO order kh0 (A,A,B,B) then kh1 (A,A,B,B)
  GLDS(Ag,      &SA[0][0][lw]);  GLDS(Ag + 16 * D_,      &SA[0][0][lw + 512]);
  GLDS(Bg,      &SB[0][0][lw]);  GLDS(Bg + 16 * D_,      &SB[0][0][lw + 512]);
  GLDS(Ag + 32, &SA[0][1][lw]);  GLDS(Ag + 32 + 16 * D_, &SA[0][1][lw + 512]);
  GLDS(Bg + 32, &SB[0][1][lw]);  GLDS(Bg + 32 + 16 * D_, &SB[0][1][lw + 512]);

  for (int kt = 0; kt < NT_ - 1; ++kt) {
    int db = kt & 1;
    const u16* An = Ag + (size_t)(kt + 1) * 64;
    const u16* AnB = Bg + (size_t)(kt + 1) * 64;
    PHASE32(db, 0, "4", 1, An);
    PHASE32(db, 1, "4", 1, An);
  }
  {
    const u16* An = Ag;   // unused (DO_ST=0)
    const u16* AnB = Bg;
    PHASE32(1, 0, "4", 0, An);
    PHASE32(1, 1, "0", 0, An);
  }

  // C/D layout 32x32 (verified m74/m101): col=lane&31, row=(q&3)+8*(q>>2)+4*(lane>>5)
  #pragma unroll
  for (int mt = 0; mt < 4; ++mt)
    #pragma unroll
    for (int nt = 0; nt < 2; ++nt)
      #pragma unroll
      for (int q = 0; q < 16; ++q) {
        int gm = m0 + wr * 128 + mt * 32 + (q & 3) + 8 * (q >> 2) + 4 * lh;
        int gn = n0 + wc * 64 + nt * 32 + l31;
        C[(size_t)gm * NN + gn] = f2b(acc[mt][nt][q]);
      }
}

// K4: fused gk + chunk-sum, 64-t chunks, grid 1024. gk stored f16;
// ct accumulated from the f16-ROUNDED values (bit-consistent with k_decay).
__global__ __launch_bounds__(256) void k_gkcs(const float* __restrict__ y,
                                              const float* __restrict__ w2,
                                              const float* __restrict__ gb,
                                              u16* __restrict__ gkh,
                                              float* __restrict__ ct) {
  __shared__ float yl[64][16];
  int blk = blockIdx.x;
  int cg = blk & 3, tc = (blk >> 2) & 63, b = blk >> 8;
  int tid = threadIdx.x;
  int c = cg * 256 + tid;
  {
    int row = tid >> 2, q = tid & 3;
    const float4* src = (const float4*)(y + (size_t)(b * T_ + tc * 64 + row) * 16 + q * 4);
    *(float4*)&yl[row][q * 4] = *src;
  }
  float w2r[16];
  {
    const float4* wsrc = (const float4*)(w2 + (size_t)c * 16);
    float4 q0 = wsrc[0], q1 = wsrc[1], q2 = wsrc[2], q3 = wsrc[3];
    w2r[0] = q0.x; w2r[1] = q0.y; w2r[2] = q0.z; w2r[3] = q0.w;
    w2r[4] = q1.x; w2r[5] = q1.y; w2r[6] = q1.z; w2r[7] = q1.w;
    w2r[8] = q2.x; w2r[9] = q2.y; w2r[10] = q2.z; w2r[11] = q2.w;
    w2r[12] = q3.x; w2r[13] = q3.y; w2r[14] = q3.z; w2r[15] = q3.w;
  }
  float gbr = gb[c];
  __syncthreads();
  float sum = 0.f;
  size_t rowbase = (size_t)(b * T_ + tc * 64) * HDK + c;
  for (int t = 0; t < 64; ++t) {
    const float4* yv4 = (const float4*)&yl[t][0];
    float4 y0 = yv4[0], y1 = yv4[1], y2 = yv4[2], y3 = yv4[3];
    float z = gbr;
    z = fmaf(y0.x, w2r[0], z);  z = fmaf(y0.y, w2r[1], z);
    z = fmaf(y0.z, w2r[2], z);  z = fmaf(y0.w, w2r[3], z);
    z = fmaf(y1.x, w2r[4], z);  z = fmaf(y1.y, w2r[5], z);
    z = fmaf(y1.z, w2r[6], z);  z = fmaf(y1.w, w2r[7], z);
    z = fmaf(y2.x, w2r[8], z);  z = fmaf(y2.y, w2r[9], z);
    z = fmaf(y2.z, w2r[10], z); z = fmaf(y2.w, w2r[11], z);
    z = fmaf(y3.x, w2r[12], z); z = fmaf(y3.y, w2r[13], z);
    z = fmaf(y3.z, w2r[14], z); z = fmaf(y3.w, w2r[15], z);
    float g = flogsig(z) * (1.f / 16.f);
    _Float16 hv = (_Float16)g;
    u16 bits; __builtin_memcpy(&bits, &hv, 2);
    gkh[rowbase + (size_t)t * HDK] = bits;
    sum += (float)hv;
  }
  ct[(size_t)(b * 64 + tc) * HDK + c] = sum;
}

// E2: scan 64 chunk sums -> exclusive offsets + totals. grid 16 (b x cg).
__global__ __launch_bounds__(256) void k_scan(const float* __restrict__ ct,
                                              float* __restrict__ co,
                                              float* __restrict__ gt) {
  int b = blockIdx.x >> 2, cg = blockIdx.x & 3;
  int c = cg * 256 + threadIdx.x;
  float run = 0.f;
  #pragma unroll 8
  for (int tc = 0; tc < 64; ++tc) {
    size_t idx = (size_t)(b * 64 + tc) * HDK + c;
    co[idx] = run;
    run += ct[idx];
  }
  gt[b * HDK + c] = run;
}

// E3: A = k * exp(g_total - G) (bf16). 64-t chunks, grid 1024.
__global__ __launch_bounds__(256) void k_decay(const u16* __restrict__ gkh,
                                               const float* __restrict__ co,
                                               const float* __restrict__ gt,
                                               const u16* __restrict__ kv,
                                               u16* __restrict__ Ab) {
  int blk = blockIdx.x;
  int cg = blk & 3, tc = (blk >> 2) & 63, b = blk >> 8;
  int c = cg * 256 + threadIdx.x;
  float run = co[(size_t)(b * 64 + tc) * HDK + c];
  float g = gt[b * HDK + c];
  #pragma unroll 8
  for (int tt = 0; tt < 64; ++tt) {
    size_t row = (size_t)(b * T_) + tc * 64 + tt;
    u16 bits = gkh[row * HDK + c];
    _Float16 hv; __builtin_memcpy(&hv, &bits, 2);
    run += (float)hv;
    float decay = fexp(g - run);
    float kvl = b2f(kv[row * NN + c]);
    Ab[row * HDK + c] = f2b(kvl * decay);
  }
}

// K6: MFMA outer product. block = (s, h, b); 8 splits x 512 t; K-steps of 32 t.
__global__ __launch_bounds__(256) void k_outer(const u16* __restrict__ Ab,
                                               const u16* __restrict__ kv,
                                               float* __restrict__ part) {
  __shared__ u16 At[2][64][40];
  __shared__ u16 Vt[2][128][40];
  int s = blockIdx.x, h = blockIdx.y, b = blockIdx.z;
  int tid = threadIdx.x;
  int w = tid >> 6, l = tid & 63;
  int adk = tid & 63, atq = tid >> 6;
  int vdv = tid & 127, vth = tid >> 7;
  int r = l & 15, q = l >> 4;
  f32x4 acc[8];
  #pragma unroll
  for (int n = 0; n < 8; ++n)
    #pragma unroll
    for (int j = 0; j < 4; ++j) acc[n][j] = 0.f;

  union { int4 v[2]; u16 u[16]; } vbuf;
  union { int4 v; u16 u[8]; } abuf;

  #define LOADT(KK) do {                                                              \
      int t0_ = s * 512 + (KK) * 32;                                                  \
      _Pragma("unroll")                                                               \
      for (int i = 0; i < 8; ++i)                                                     \
        abuf.u[i] = Ab[(size_t)(b * T_ + t0_ + atq * 8 + i) * HDK + h * DK_ + adk];   \
      _Pragma("unroll")                                                               \
      for (int i = 0; i < 16; ++i)                                                    \
        vbuf.u[i] = kv[(size_t)(b * T_ + t0_ + vth * 16 + i) * NN + HDK + h * DV_ + vdv]; \
    } while (0)

  #define WRITET(BF) do {                                                             \
      *(int4*)&At[BF][adk][atq * 8] = abuf.v;                                         \
      *(int4*)&Vt[BF][vdv][vth * 16] = vbuf.v[0];                                     \
      *(int4*)&Vt[BF][vdv][vth * 16 + 8] = vbuf.v[1];                                 \
    } while (0)

  LOADT(0);
  WRITET(0);
  for (int kk = 0; kk < 16; ++kk) {
    int cur = kk & 1;
    if (kk < 15) LOADT(kk + 1);
    __syncthreads();
    bf16x8 af = *(const bf16x8*)&At[cur][w * 16 + r][q * 8];
    #pragma unroll
    for (int n = 0; n < 8; ++n) {
      bf16x8 vf = *(const bf16x8*)&Vt[cur][n * 16 + r][q * 8];
      acc[n] = __builtin_amdgcn_mfma_f32_16x16x32_bf16(af, vf, acc[n], 0, 0, 0);
    }
    __syncthreads();
    if (kk < 15) WRITET(1 - cur);
  }
  #undef LOADT
  #undef WRITET

  float* dst = part + ((size_t)(b * H_ + h) * 8 + s) * (DK_ * DV_);
  #pragma unroll
  for (int n = 0; n < 8; ++n)
    #pragma unroll
    for (int j = 0; j < 4; ++j)
      dst[(w * 16 + q * 4 + j) * DV_ + n * 16 + r] = acc[n][j];
}

// K7: out = exp(g_total)*state + sum over 8 splits
__global__ __launch_bounds__(256) void k_final(const float* __restrict__ part,
                                               const float* __restrict__ gt,
                                               const float* __restrict__ st,
                                               float* __restrict__ out) {
  int i = blockIdx.x * 256 + threadIdx.x;
  int dv = i & 127, dk = (i >> 7) & 63, h = (i >> 13) & 15, b = i >> 17;
  size_t base = ((size_t)(b * H_ + h) * 8) * 8192 + dk * DV_ + dv;
  float s = 0.f;
  #pragma unroll
  for (int sp = 0; sp < 8; ++sp) s += part[base + (size_t)sp * 8192];
  float g = gt[b * HDK + h * DK_ + dk];
  out[i] = fexp(g) * st[i] + s;
}

extern "C" void kernel_launch(void* const* d_in, const int* in_sizes, int n_in,
                              void* d_out, int out_size, void* d_ws, size_t ws_size,
                              hipStream_t stream) {
  const float* hs = (const float*)d_in[0];
  const float* st = (const float*)d_in[1];
  const float* nw = (const float*)d_in[2];
  const float* kw = (const float*)d_in[3];
  const float* vw = (const float*)d_in[4];
  const float* w1 = (const float*)d_in[5];
  const float* w2 = (const float*)d_in[6];
  const float* gb = (const float*)d_in[7];
  float* out = (float*)d_out;
  char* ws = (char*)d_ws;

  u16*  Wb  = (u16*)(ws + 0);              // 12,582,912
  u16*  xb  = (u16*)(ws + 12582912);       // 67,108,864 (dead after gemm)
  float* y  = (float*)(ws + 79691776);     //  1,048,576
  u16*  kv  = (u16*)(ws + 80740352);       // 100,663,296
  u16*  gkh = (u16*)(ws + 181403648);      // 33,554,432 (f16)
  float* ct = (float*)(ws + 214958080);    //  1,048,576
  float* co = (float*)(ws + 216006656);    //  1,048,576
  float* gt = (float*)(ws + 217055232);    //     16,384
  u16*  Ab  = (u16*)(ws + 12582912);              // reuse xb region (33.5 MB)
  float* part = (float*)(ws + 12582912 + 33554432); // 16,777,216

  k_cvtw<<<dim3(3072), dim3(256), 0, stream>>>(kw, vw, Wb);
  k_rms<<<dim3(4096), dim3(256), 0, stream>>>(hs, nw, w1, xb, y);
  k_gemm<<<dim3(768), dim3(512), 0, stream>>>(xb, Wb, kv);
  k_gkcs<<<dim3(1024), dim3(256), 0, stream>>>(y, w2, gb, gkh, ct);
  k_scan<<<dim3(16), dim3(256), 0, stream>>>(ct, co, gt);
  k_decay<<<dim3(1024), dim3(256), 0, stream>>>(gkh, co, gt, kv, Ab);
  k_outer<<<dim3(8, 16, 4), dim3(256), 0, stream>>>(Ab, kv, part);
  k_final<<<dim3(2048), dim3(256), 0, stream>>>(part, gt, st, out);
}

// Round 15
// 365.578 us; speedup vs baseline: 1.1868x; 1.0313x over previous
//
#include <hip/hip_runtime.h>

#define B_ 4
#define T_ 4096
#define D_ 2048
#define H_ 16
#define DK_ 64
#define DV_ 128
#define HDK 1024
#define HDV 2048
#define NN 3072
#define MM 16384
#define NT_ 32  // D_/64 K-tiles (BK=64)

typedef unsigned short u16;
typedef unsigned int u32;
typedef __attribute__((ext_vector_type(8))) short bf16x8;
typedef __attribute__((ext_vector_type(4))) float f32x4;

typedef const __attribute__((address_space(1))) u16 gu16;
typedef __attribute__((address_space(3))) u16 lu16;

__device__ __forceinline__ float b2f(u16 u) {
  u32 x = ((u32)u) << 16; float f; __builtin_memcpy(&f, &x, 4); return f;
}
__device__ __forceinline__ u16 f2b(float f) {
  u32 x; __builtin_memcpy(&x, &f, 4);
  u32 r = x + 0x7FFFu + ((x >> 16) & 1u);
  return (u16)(r >> 16);
}
__device__ __forceinline__ float fexp(float x) { return exp2f(x * 1.44269504f); }
__device__ __forceinline__ float flogsig(float z) {
  float u = exp2f(-fabsf(z) * 1.44269504f);
  float l = log2f(1.f + u) * 0.69314718f;
  return fminf(z, 0.f) - l;
}

// K1: convert [k_w; v_w] (3072 x 2048 f32) -> bf16
__global__ __launch_bounds__(256) void k_cvtw(const float* __restrict__ kw,
                                              const float* __restrict__ vw,
                                              u16* __restrict__ Wb) {
  int i = blockIdx.x * 256 + threadIdx.x;
  size_t e = (size_t)i * 8;
  const float* src = (e < (size_t)HDK * D_) ? (kw + e) : (vw + (e - (size_t)HDK * D_));
  float4 f0 = ((const float4*)src)[0];
  float4 f1 = ((const float4*)src)[1];
  union { int4 v; u16 u[8]; } o;
  o.u[0] = f2b(f0.x); o.u[1] = f2b(f0.y); o.u[2] = f2b(f0.z); o.u[3] = f2b(f0.w);
  o.u[4] = f2b(f1.x); o.u[5] = f2b(f1.y); o.u[6] = f2b(f1.z); o.u[7] = f2b(f1.w);
  *(int4*)(Wb + e) = o.v;
}

// K2: RMSNorm -> x (bf16), and y = x @ gk_w1^T (f32, 16 per row). 4 rows/block.
// (R3/R5-proven version.)
__global__ __launch_bounds__(256) void k_rms(const float* __restrict__ hs,
                                             const float* __restrict__ nw,
                                             const float* __restrict__ w1,
                                             u16* __restrict__ xb,
                                             float* __restrict__ y) {
  int r0 = blockIdx.x * 4;
  int tid = threadIdx.x;
  int wv = tid >> 6, ln = tid & 63;
  __shared__ float red[4][4];
  __shared__ float ys[4][4][16];
  float x[4][8];
  float ssq[4];
  #pragma unroll
  for (int r = 0; r < 4; ++r) {
    const float4* hp = (const float4*)(hs + (size_t)(r0 + r) * D_);
    float4 a = hp[tid * 2], b = hp[tid * 2 + 1];
    x[r][0] = a.x; x[r][1] = a.y; x[r][2] = a.z; x[r][3] = a.w;
    x[r][4] = b.x; x[r][5] = b.y; x[r][6] = b.z; x[r][7] = b.w;
    float s = 0.f;
    #pragma unroll
    for (int i = 0; i < 8; ++i) s += x[r][i] * x[r][i];
    #pragma unroll
    for (int o = 32; o > 0; o >>= 1) s += __shfl_xor(s, o, 64);
    ssq[r] = s;
  }
  if (ln == 0) {
    #pragma unroll
    for (int r = 0; r < 4; ++r) red[wv][r] = ssq[r];
  }
  __syncthreads();
  const float4* np_ = (const float4*)nw;
  float4 n0 = np_[tid * 2], n1 = np_[tid * 2 + 1];
  float nwv[8] = {n0.x, n0.y, n0.z, n0.w, n1.x, n1.y, n1.z, n1.w};
  #pragma unroll
  for (int r = 0; r < 4; ++r) {
    float tot = red[0][r] + red[1][r] + red[2][r] + red[3][r];
    float inv = rsqrtf(tot * (1.f / D_) + 1e-5f);
    union { int4 v; u16 u[8]; } o;
    #pragma unroll
    for (int i = 0; i < 8; ++i) { x[r][i] = x[r][i] * inv * nwv[i]; o.u[i] = f2b(x[r][i]); }
    *(int4*)(xb + (size_t)(r0 + r) * D_ + tid * 8) = o.v;
  }
  float p[4][16];
  #pragma unroll
  for (int r = 0; r < 4; ++r)
    #pragma unroll
    for (int j = 0; j < 16; ++j) p[r][j] = 0.f;
  #pragma unroll
  for (int j = 0; j < 16; ++j) {
    const float4* wp = (const float4*)(w1 + (size_t)j * D_);
    float4 a = wp[tid * 2], b = wp[tid * 2 + 1];
    float wj[8] = {a.x, a.y, a.z, a.w, b.x, b.y, b.z, b.w};
    #pragma unroll
    for (int r = 0; r < 4; ++r) {
      float s = 0.f;
      #pragma unroll
      for (int i = 0; i < 8; ++i) s += x[r][i] * wj[i];
      p[r][j] = s;
    }
  }
  #pragma unroll
  for (int r = 0; r < 4; ++r)
    #pragma unroll
    for (int j = 0; j < 16; ++j) {
      float s = p[r][j];
      #pragma unroll
      for (int o = 32; o > 0; o >>= 1) s += __shfl_xor(s, o, 64);
      p[r][j] = s;
    }
  if (ln == 0) {
    for (int r = 0; r < 4; ++r)
      for (int j = 0; j < 16; ++j) ys[wv][r][j] = p[r][j];
  }
  __syncthreads();
  if (tid < 64) {
    int r = tid >> 4, j = tid & 15;
    y[(size_t)(r0 + r) * 16 + j] = ys[0][r][j] + ys[1][r][j] + ys[2][r][j] + ys[3][r][j];
  }
}

// K3: kv = x @ Wb^T. 256x256 tile, 8 waves, BK=64, 2 dbuf x 2 k-half LDS,
// R7/R11-proven staging & swizzle & 16x16 fragments.
// NEW (R15, T14 issue-early): each phase's 4 GLDS issued BEFORE the
// vmcnt+barrier (latency hides under prior MFMA + barrier drain).
// Safety: SA[nb][0] last read kt-1 P0/P1 (all waves done before kt-1's P2
// barrier); SA[nb][1] last read kt-1 P3 (protected by this tile's P0 barrier).
// FIFO [kt-1P0:4][kt-1P2:4][ktP0:4] -> vmcnt(8) at both syncs; last tile 4/0.
#define GLDS(SRC, DST) __builtin_amdgcn_global_load_lds((gu16*)(SRC), (lu16*)(DST), 16, 0, 0)

#define MFMA16(AF, MB) do {                                                    \
    __builtin_amdgcn_s_setprio(1);                                             \
    _Pragma("unroll")                                                          \
    for (int mi_ = 0; mi_ < 4; ++mi_)                                          \
      _Pragma("unroll")                                                        \
      for (int ni_ = 0; ni_ < 4; ++ni_)                                        \
        acc[(MB) + mi_][ni_] = __builtin_amdgcn_mfma_f32_16x16x32_bf16(        \
            AF[mi_], bf[ni_], acc[(MB) + mi_][ni_], 0, 0, 0);                  \
    __builtin_amdgcn_s_setprio(0);                                             \
    __builtin_amdgcn_sched_barrier(0);                                         \
  } while (0)

#define KTILE(DB, NB, VM0, VM2, ST) do {                                       \
    /* stage next kh0 EARLY, then sync, then compute kh0 */                    \
    if (ST) { GLDS(An, &SA[NB][0][lw]); GLDS(An + 16 * D_, &SA[NB][0][lw + 512]); \
              GLDS(Bn, &SB[NB][0][lw]); GLDS(Bn + 16 * D_, &SB[NB][0][lw + 512]); } \
    __builtin_amdgcn_sched_barrier(0);                                         \
    asm volatile("s_waitcnt vmcnt(" VM0 ")" ::: "memory");                     \
    __builtin_amdgcn_s_barrier();                                              \
    __builtin_amdgcn_sched_barrier(0);                                         \
    _Pragma("unroll")                                                          \
    for (int mi_ = 0; mi_ < 4; ++mi_)                                          \
      af[mi_] = *(const bf16x8*)&SA[DB][0][(wr * 128 + mi_ * 16 + r) * 32 + kcol]; \
    _Pragma("unroll")                                                          \
    for (int ni_ = 0; ni_ < 4; ++ni_)                                          \
      bf[ni_] = *(const bf16x8*)&SB[DB][0][(wc * 64 + ni_ * 16 + r) * 32 + kcol]; \
    asm volatile("s_waitcnt lgkmcnt(0)" ::: "memory");                         \
    __builtin_amdgcn_sched_barrier(0);                                         \
    MFMA16(af, 0);                                                             \
    _Pragma("unroll")                                                          \
    for (int mi_ = 0; mi_ < 4; ++mi_)                                          \
      af2[mi_] = *(const bf16x8*)&SA[DB][0][(wr * 128 + (4 + mi_) * 16 + r) * 32 + kcol]; \
    asm volatile("s_waitcnt lgkmcnt(0)" ::: "memory");                         \
    __builtin_amdgcn_sched_barrier(0);                                         \
    MFMA16(af2, 4);                                                            \
    /* stage next kh1 EARLY (post-P0-barrier => kt-1 P3 reads done), sync, kh1 */ \
    if (ST) { GLDS(An + 32, &SA[NB][1][lw]); GLDS(An + 32 + 16 * D_, &SA[NB][1][lw + 512]); \
              GLDS(Bn + 32, &SB[NB][1][lw]); GLDS(Bn + 32 + 16 * D_, &SB[NB][1][lw + 512]); } \
    __builtin_amdgcn_sched_barrier(0);                                         \
    asm volatile("s_waitcnt vmcnt(" VM2 ")" ::: "memory");                     \
    __builtin_amdgcn_s_barrier();                                              \
    __builtin_amdgcn_sched_barrier(0);                                         \
    _Pragma("unroll")                                                          \
    for (int mi_ = 0; mi_ < 4; ++mi_)                                          \
      af[mi_] = *(const bf16x8*)&SA[DB][1][(wr * 128 + mi_ * 16 + r) * 32 + kcol]; \
    _Pragma("unroll")                                                          \
    for (int ni_ = 0; ni_ < 4; ++ni_)                                          \
      bf[ni_] = *(const bf16x8*)&SB[DB][1][(wc * 64 + ni_ * 16 + r) * 32 + kcol]; \
    asm volatile("s_waitcnt lgkmcnt(0)" ::: "memory");                         \
    __builtin_amdgcn_sched_barrier(0);                                         \
    MFMA16(af, 0);                                                             \
    _Pragma("unroll")                                                          \
    for (int mi_ = 0; mi_ < 4; ++mi_)                                          \
      af2[mi_] = *(const bf16x8*)&SA[DB][1][(wr * 128 + (4 + mi_) * 16 + r) * 32 + kcol]; \
    asm volatile("s_waitcnt lgkmcnt(0)" ::: "memory");                         \
    __builtin_amdgcn_sched_barrier(0);                                         \
    MFMA16(af2, 4);                                                            \
  } while (0)

__global__ __launch_bounds__(512, 2) void k_gemm(const u16* __restrict__ X,
                                                 const u16* __restrict__ W,
                                                 u16* __restrict__ C) {
  __shared__ u16 SA[2][2][8192];  // [dbuf][k-half][256 rows x 32 cols]
  __shared__ u16 SB[2][2][8192];
  int bid = blockIdx.x;
  int swzb = (bid & 7) * 96 + (bid >> 3);   // bijective XCD swizzle (768%8==0)
  int tm = swzb / 12, tn = swzb - tm * 12;
  int m0 = tm << 8, n0 = tn << 8;
  int tid = threadIdx.x;
  int w = tid >> 6, l = tid & 63;
  int wr = w >> 2, wc = w & 3;
  int arow = w * 32 + (l >> 2);
  int csw = 8 * ((l & 3) ^ ((l >> 3) & 3));
  const u16* Ag = X + (size_t)(m0 + arow) * D_ + csw;
  const u16* Bg = W + (size_t)(n0 + arow) * D_ + csw;
  int lw = w * 1024;
  int r = l & 15, kq = l >> 4;
  int kcol = 8 * (kq ^ ((r >> 1) & 3));

  f32x4 acc[8][4];
  #pragma unroll
  for (int mi = 0; mi < 8; ++mi)
    #pragma unroll
    for (int ni = 0; ni < 4; ++ni)
      #pragma unroll
      for (int q = 0; q < 4; ++q) acc[mi][ni][q] = 0.f;

  bf16x8 af[4], af2[4], bf[4];

  // prologue: tile 0, FIFO order kh0(4) then kh1(4)
  GLDS(Ag,      &SA[0][0][lw]);  GLDS(Ag + 16 * D_,      &SA[0][0][lw + 512]);
  GLDS(Bg,      &SB[0][0][lw]);  GLDS(Bg + 16 * D_,      &SB[0][0][lw + 512]);
  GLDS(Ag + 32, &SA[0][1][lw]);  GLDS(Ag + 32 + 16 * D_, &SA[0][1][lw + 512]);
  GLDS(Bg + 32, &SB[0][1][lw]);  GLDS(Bg + 32 + 16 * D_, &SB[0][1][lw + 512]);

  for (int kt = 0; kt < NT_ - 1; ++kt) {
    int db = kt & 1, nb = db ^ 1;
    const u16* An = Ag + (size_t)(kt + 1) * 64;
    const u16* Bn = Bg + (size_t)(kt + 1) * 64;
    KTILE(db, nb, "8", "8", 1);
  }
  {
    const u16* An = Ag;  // unused (ST=0)
    const u16* Bn = Bg;
    KTILE(1, 0, "4", "0", 0);
  }

  int cr = (l >> 4) * 4, cc = l & 15;
  #pragma unroll
  for (int mi = 0; mi < 8; ++mi)
    #pragma unroll
    for (int ni = 0; ni < 4; ++ni)
      #pragma unroll
      for (int q = 0; q < 4; ++q) {
        int gm = m0 + wr * 128 + mi * 16 + cr + q;
        int gn = n0 + wc * 64 + ni * 16 + cc;
        C[(size_t)gm * NN + gn] = f2b(acc[mi][ni][q]);
      }
}

// K4: fused gk + chunk-sum, 64-t chunks, grid 1024. gk stored f16;
// ct accumulated from the f16-ROUNDED values (bit-consistent with k_decay).
__global__ __launch_bounds__(256) void k_gkcs(const float* __restrict__ y,
                                              const float* __restrict__ w2,
                                              const float* __restrict__ gb,
                                              u16* __restrict__ gkh,
                                              float* __restrict__ ct) {
  __shared__ float yl[64][16];
  int blk = blockIdx.x;
  int cg = blk & 3, tc = (blk >> 2) & 63, b = blk >> 8;
  int tid = threadIdx.x;
  int c = cg * 256 + tid;
  {
    int row = tid >> 2, q = tid & 3;
    const float4* src = (const float4*)(y + (size_t)(b * T_ + tc * 64 + row) * 16 + q * 4);
    *(float4*)&yl[row][q * 4] = *src;
  }
  float w2r[16];
  {
    const float4* wsrc = (const float4*)(w2 + (size_t)c * 16);
    float4 q0 = wsrc[0], q1 = wsrc[1], q2 = wsrc[2], q3 = wsrc[3];
    w2r[0] = q0.x; w2r[1] = q0.y; w2r[2] = q0.z; w2r[3] = q0.w;
    w2r[4] = q1.x; w2r[5] = q1.y; w2r[6] = q1.z; w2r[7] = q1.w;
    w2r[8] = q2.x; w2r[9] = q2.y; w2r[10] = q2.z; w2r[11] = q2.w;
    w2r[12] = q3.x; w2r[13] = q3.y; w2r[14] = q3.z; w2r[15] = q3.w;
  }
  float gbr = gb[c];
  __syncthreads();
  float sum = 0.f;
  size_t rowbase = (size_t)(b * T_ + tc * 64) * HDK + c;
  for (int t = 0; t < 64; ++t) {
    const float4* yv4 = (const float4*)&yl[t][0];
    float4 y0 = yv4[0], y1 = yv4[1], y2 = yv4[2], y3 = yv4[3];
    float z = gbr;
    z = fmaf(y0.x, w2r[0], z);  z = fmaf(y0.y, w2r[1], z);
    z = fmaf(y0.z, w2r[2], z);  z = fmaf(y0.w, w2r[3], z);
    z = fmaf(y1.x, w2r[4], z);  z = fmaf(y1.y, w2r[5], z);
    z = fmaf(y1.z, w2r[6], z);  z = fmaf(y1.w, w2r[7], z);
    z = fmaf(y2.x, w2r[8], z);  z = fmaf(y2.y, w2r[9], z);
    z = fmaf(y2.z, w2r[10], z); z = fmaf(y2.w, w2r[11], z);
    z = fmaf(y3.x, w2r[12], z); z = fmaf(y3.y, w2r[13], z);
    z = fmaf(y3.z, w2r[14], z); z = fmaf(y3.w, w2r[15], z);
    float g = flogsig(z) * (1.f / 16.f);
    _Float16 hv = (_Float16)g;
    u16 bits; __builtin_memcpy(&bits, &hv, 2);
    gkh[rowbase + (size_t)t * HDK] = bits;
    sum += (float)hv;
  }
  ct[(size_t)(b * 64 + tc) * HDK + c] = sum;
}

// E2: scan 64 chunk sums -> exclusive offsets + totals. grid 16 (b x cg).
__global__ __launch_bounds__(256) void k_scan(const float* __restrict__ ct,
                                              float* __restrict__ co,
                                              float* __restrict__ gt) {
  int b = blockIdx.x >> 2, cg = blockIdx.x & 3;
  int c = cg * 256 + threadIdx.x;
  float run = 0.f;
  #pragma unroll 8
  for (int tc = 0; tc < 64; ++tc) {
    size_t idx = (size_t)(b * 64 + tc) * HDK + c;
    co[idx] = run;
    run += ct[idx];
  }
  gt[b * HDK + c] = run;
}

// E3: A = k * exp(g_total - G) (bf16). 64-t chunks, grid 1024.
__global__ __launch_bounds__(256) void k_decay(const u16* __restrict__ gkh,
                                               const float* __restrict__ co,
                                               const float* __restrict__ gt,
                                               const u16* __restrict__ kv,
                                               u16* __restrict__ Ab) {
  int blk = blockIdx.x;
  int cg = blk & 3, tc = (blk >> 2) & 63, b = blk >> 8;
  int c = cg * 256 + threadIdx.x;
  float run = co[(size_t)(b * 64 + tc) * HDK + c];
  float g = gt[b * HDK + c];
  #pragma unroll 8
  for (int tt = 0; tt < 64; ++tt) {
    size_t row = (size_t)(b * T_) + tc * 64 + tt;
    u16 bits = gkh[row * HDK + c];
    _Float16 hv; __builtin_memcpy(&hv, &bits, 2);
    run += (float)hv;
    float decay = fexp(g - run);
    float kvl = b2f(kv[row * NN + c]);
    Ab[row * HDK + c] = f2b(kvl * decay);
  }
}

// K6: MFMA outer product. block = (s, h, b); 8 splits x 512 t; K-steps of 32 t.
__global__ __launch_bounds__(256) void k_outer(const u16* __restrict__ Ab,
                                               const u16* __restrict__ kv,
                                               float* __restrict__ part) {
  __shared__ u16 At[2][64][40];
  __shared__ u16 Vt[2][128][40];
  int s = blockIdx.x, h = blockIdx.y, b = blockIdx.z;
  int tid = threadIdx.x;
  int w = tid >> 6, l = tid & 63;
  int adk = tid & 63, atq = tid >> 6;
  int vdv = tid & 127, vth = tid >> 7;
  int r = l & 15, q = l >> 4;
  f32x4 acc[8];
  #pragma unroll
  for (int n = 0; n < 8; ++n)
    #pragma unroll
    for (int j = 0; j < 4; ++j) acc[n][j] = 0.f;

  union { int4 v[2]; u16 u[16]; } vbuf;
  union { int4 v; u16 u[8]; } abuf;

  #define LOADT(KK) do {                                                              \
      int t0_ = s * 512 + (KK) * 32;                                                  \
      _Pragma("unroll")                                                               \
      for (int i = 0; i < 8; ++i)                                                     \
        abuf.u[i] = Ab[(size_t)(b * T_ + t0_ + atq * 8 + i) * HDK + h * DK_ + adk];   \
      _Pragma("unroll")                                                               \
      for (int i = 0; i < 16; ++i)                                                    \
        vbuf.u[i] = kv[(size_t)(b * T_ + t0_ + vth * 16 + i) * NN + HDK + h * DV_ + vdv]; \
    } while (0)

  #define WRITET(BF) do {                                                             \
      *(int4*)&At[BF][adk][atq * 8] = abuf.v;                                         \
      *(int4*)&Vt[BF][vdv][vth * 16] = vbuf.v[0];                                     \
      *(int4*)&Vt[BF][vdv][vth * 16 + 8] = vbuf.v[1];                                 \
    } while (0)

  LOADT(0);
  WRITET(0);
  for (int kk = 0; kk < 16; ++kk) {
    int cur = kk & 1;
    if (kk < 15) LOADT(kk + 1);
    __syncthreads();
    bf16x8 af = *(const bf16x8*)&At[cur][w * 16 + r][q * 8];
    #pragma unroll
    for (int n = 0; n < 8; ++n) {
      bf16x8 vf = *(const bf16x8*)&Vt[cur][n * 16 + r][q * 8];
      acc[n] = __builtin_amdgcn_mfma_f32_16x16x32_bf16(af, vf, acc[n], 0, 0, 0);
    }
    __syncthreads();
    if (kk < 15) WRITET(1 - cur);
  }
  #undef LOADT
  #undef WRITET

  float* dst = part + ((size_t)(b * H_ + h) * 8 + s) * (DK_ * DV_);
  #pragma unroll
  for (int n = 0; n < 8; ++n)
    #pragma unroll
    for (int j = 0; j < 4; ++j)
      dst[(w * 16 + q * 4 + j) * DV_ + n * 16 + r] = acc[n][j];
}

// K7: out = exp(g_total)*state + sum over 8 splits
__global__ __launch_bounds__(256) void k_final(const float* __restrict__ part,
                                               const float* __restrict__ gt,
                                               const float* __restrict__ st,
                                               float* __restrict__ out) {
  int i = blockIdx.x * 256 + threadIdx.x;
  int dv = i & 127, dk = (i >> 7) & 63, h = (i >> 13) & 15, b = i >> 17;
  size_t base = ((size_t)(b * H_ + h) * 8) * 8192 + dk * DV_ + dv;
  float s = 0.f;
  #pragma unroll
  for (int sp = 0; sp < 8; ++sp) s += part[base + (size_t)sp * 8192];
  float g = gt[b * HDK + h * DK_ + dk];
  out[i] = fexp(g) * st[i] + s;
}

extern "C" void kernel_launch(void* const* d_in, const int* in_sizes, int n_in,
                              void* d_out, int out_size, void* d_ws, size_t ws_size,
                              hipStream_t stream) {
  const float* hs = (const float*)d_in[0];
  const float* st = (const float*)d_in[1];
  const float* nw = (const float*)d_in[2];
  const float* kw = (const float*)d_in[3];
  const float* vw = (const float*)d_in[4];
  const float* w1 = (const float*)d_in[5];
  const float* w2 = (const float*)d_in[6];
  const float* gb = (const float*)d_in[7];
  float* out = (float*)d_out;
  char* ws = (char*)d_ws;

  u16*  Wb  = (u16*)(ws + 0);              // 12,582,912
  u16*  xb  = (u16*)(ws + 12582912);       // 67,108,864 (dead after gemm)
  float* y  = (float*)(ws + 79691776);     //  1,048,576
  u16*  kv  = (u16*)(ws + 80740352);       // 100,663,296
  u16*  gkh = (u16*)(ws + 181403648);      // 33,554,432 (f16)
  float* ct = (float*)(ws + 214958080);    //  1,048,576
  float* co = (float*)(ws + 216006656);    //  1,048,576
  float* gt = (float*)(ws + 217055232);    //     16,384
  u16*  Ab  = (u16*)(ws + 12582912);              // reuse xb region (33.5 MB)
  float* part = (float*)(ws + 12582912 + 33554432); // 16,777,216

  k_cvtw<<<dim3(3072), dim3(256), 0, stream>>>(kw, vw, Wb);
  k_rms<<<dim3(4096), dim3(256), 0, stream>>>(hs, nw, w1, xb, y);
  k_gemm<<<dim3(768), dim3(512), 0, stream>>>(xb, Wb, kv);
  k_gkcs<<<dim3(1024), dim3(256), 0, stream>>>(y, w2, gb, gkh, ct);
  k_scan<<<dim3(16), dim3(256), 0, stream>>>(ct, co, gt);
  k_decay<<<dim3(1024), dim3(256), 0, stream>>>(gkh, co, gt, kv, Ab);
  k_outer<<<dim3(8, 16, 4), dim3(256), 0, stream>>>(Ab, kv, part);
  k_final<<<dim3(2048), dim3(256), 0, stream>>>(part, gt, st, out);
}

// Round 16
// 354.162 us; speedup vs baseline: 1.2251x; 1.0322x over previous
//
#include <hip/hip_runtime.h>

#define B_ 4
#define T_ 4096
#define D_ 2048
#define H_ 16
#define DK_ 64
#define DV_ 128
#define HDK 1024
#define HDV 2048
#define NN 3072
#define MM 16384
#define NT_ 32  // D_/64 K-tiles (BK=64)

typedef unsigned short u16;
typedef unsigned int u32;
typedef __attribute__((ext_vector_type(8))) short bf16x8;
typedef __attribute__((ext_vector_type(4))) float f32x4;

typedef const __attribute__((address_space(1))) u16 gu16;
typedef __attribute__((address_space(3))) u16 lu16;

__device__ __forceinline__ float b2f(u16 u) {
  u32 x = ((u32)u) << 16; float f; __builtin_memcpy(&f, &x, 4); return f;
}
__device__ __forceinline__ u16 f2b(float f) {
  u32 x; __builtin_memcpy(&x, &f, 4);
  u32 r = x + 0x7FFFu + ((x >> 16) & 1u);
  return (u16)(r >> 16);
}
__device__ __forceinline__ float fexp(float x) { return exp2f(x * 1.44269504f); }
__device__ __forceinline__ float flogsig(float z) {
  float u = exp2f(-fabsf(z) * 1.44269504f);
  float l = log2f(1.f + u) * 0.69314718f;
  return fminf(z, 0.f) - l;
}

// K1: convert [k_w; v_w] (3072 x 2048 f32) -> bf16
__global__ __launch_bounds__(256) void k_cvtw(const float* __restrict__ kw,
                                              const float* __restrict__ vw,
                                              u16* __restrict__ Wb) {
  int i = blockIdx.x * 256 + threadIdx.x;
  size_t e = (size_t)i * 8;
  const float* src = (e < (size_t)HDK * D_) ? (kw + e) : (vw + (e - (size_t)HDK * D_));
  float4 f0 = ((const float4*)src)[0];
  float4 f1 = ((const float4*)src)[1];
  union { int4 v; u16 u[8]; } o;
  o.u[0] = f2b(f0.x); o.u[1] = f2b(f0.y); o.u[2] = f2b(f0.z); o.u[3] = f2b(f0.w);
  o.u[4] = f2b(f1.x); o.u[5] = f2b(f1.y); o.u[6] = f2b(f1.z); o.u[7] = f2b(f1.w);
  *(int4*)(Wb + e) = o.v;
}

// K2: RMSNorm -> x (bf16), and y = x @ gk_w1^T (f32, 16 per row). 4 rows/block.
// (R3/R5-proven version.)
__global__ __launch_bounds__(256) void k_rms(const float* __restrict__ hs,
                                             const float* __restrict__ nw,
                                             const float* __restrict__ w1,
                                             u16* __restrict__ xb,
                                             float* __restrict__ y) {
  int r0 = blockIdx.x * 4;
  int tid = threadIdx.x;
  int wv = tid >> 6, ln = tid & 63;
  __shared__ float red[4][4];
  __shared__ float ys[4][4][16];
  float x[4][8];
  float ssq[4];
  #pragma unroll
  for (int r = 0; r < 4; ++r) {
    const float4* hp = (const float4*)(hs + (size_t)(r0 + r) * D_);
    float4 a = hp[tid * 2], b = hp[tid * 2 + 1];
    x[r][0] = a.x; x[r][1] = a.y; x[r][2] = a.z; x[r][3] = a.w;
    x[r][4] = b.x; x[r][5] = b.y; x[r][6] = b.z; x[r][7] = b.w;
    float s = 0.f;
    #pragma unroll
    for (int i = 0; i < 8; ++i) s += x[r][i] * x[r][i];
    #pragma unroll
    for (int o = 32; o > 0; o >>= 1) s += __shfl_xor(s, o, 64);
    ssq[r] = s;
  }
  if (ln == 0) {
    #pragma unroll
    for (int r = 0; r < 4; ++r) red[wv][r] = ssq[r];
  }
  __syncthreads();
  const float4* np_ = (const float4*)nw;
  float4 n0 = np_[tid * 2], n1 = np_[tid * 2 + 1];
  float nwv[8] = {n0.x, n0.y, n0.z, n0.w, n1.x, n1.y, n1.z, n1.w};
  #pragma unroll
  for (int r = 0; r < 4; ++r) {
    float tot = red[0][r] + red[1][r] + red[2][r] + red[3][r];
    float inv = rsqrtf(tot * (1.f / D_) + 1e-5f);
    union { int4 v; u16 u[8]; } o;
    #pragma unroll
    for (int i = 0; i < 8; ++i) { x[r][i] = x[r][i] * inv * nwv[i]; o.u[i] = f2b(x[r][i]); }
    *(int4*)(xb + (size_t)(r0 + r) * D_ + tid * 8) = o.v;
  }
  float p[4][16];
  #pragma unroll
  for (int r = 0; r < 4; ++r)
    #pragma unroll
    for (int j = 0; j < 16; ++j) p[r][j] = 0.f;
  #pragma unroll
  for (int j = 0; j < 16; ++j) {
    const float4* wp = (const float4*)(w1 + (size_t)j * D_);
    float4 a = wp[tid * 2], b = wp[tid * 2 + 1];
    float wj[8] = {a.x, a.y, a.z, a.w, b.x, b.y, b.z, b.w};
    #pragma unroll
    for (int r = 0; r < 4; ++r) {
      float s = 0.f;
      #pragma unroll
      for (int i = 0; i < 8; ++i) s += x[r][i] * wj[i];
      p[r][j] = s;
    }
  }
  #pragma unroll
  for (int r = 0; r < 4; ++r)
    #pragma unroll
    for (int j = 0; j < 16; ++j) {
      float s = p[r][j];
      #pragma unroll
      for (int o = 32; o > 0; o >>= 1) s += __shfl_xor(s, o, 64);
      p[r][j] = s;
    }
  if (ln == 0) {
    for (int r = 0; r < 4; ++r)
      for (int j = 0; j < 16; ++j) ys[wv][r][j] = p[r][j];
  }
  __syncthreads();
  if (tid < 64) {
    int r = tid >> 4, j = tid & 15;
    y[(size_t)(r0 + r) * 16 + j] = ys[0][r][j] + ys[1][r][j] + ys[2][r][j] + ys[3][r][j];
  }
}

// K3: kv = x @ Wb^T. R11-proven verbatim (best measured ~200us): 256x256,
// 8 waves, BK=64, 2dbuf x 2kh, 4-phase KTILE, vmcnt(2)@P0 / vmcnt(4)@P2.
#define GLDS(SRC, DST) __builtin_amdgcn_global_load_lds((gu16*)(SRC), (lu16*)(DST), 16, 0, 0)

#define MFMA16(AF, MB) do {                                                    \
    __builtin_amdgcn_s_setprio(1);                                             \
    _Pragma("unroll")                                                          \
    for (int mi_ = 0; mi_ < 4; ++mi_)                                          \
      _Pragma("unroll")                                                        \
      for (int ni_ = 0; ni_ < 4; ++ni_)                                        \
        acc[(MB) + mi_][ni_] = __builtin_amdgcn_mfma_f32_16x16x32_bf16(        \
            AF[mi_], bf[ni_], acc[(MB) + mi_][ni_], 0, 0, 0);                  \
    __builtin_amdgcn_s_setprio(0);                                             \
    __builtin_amdgcn_sched_barrier(0);                                         \
  } while (0)

#define KTILE(DB, NB, VM0, VM2, ST) do {                                       \
    asm volatile("s_waitcnt vmcnt(" VM0 ")" ::: "memory");                     \
    __builtin_amdgcn_s_barrier();                                              \
    __builtin_amdgcn_sched_barrier(0);                                         \
    _Pragma("unroll")                                                          \
    for (int mi_ = 0; mi_ < 4; ++mi_)                                          \
      af[mi_] = *(const bf16x8*)&SA[DB][0][(wr * 128 + mi_ * 16 + r) * 32 + kcol]; \
    _Pragma("unroll")                                                          \
    for (int ni_ = 0; ni_ < 4; ++ni_)                                          \
      bf[ni_] = *(const bf16x8*)&SB[DB][0][(wc * 64 + ni_ * 16 + r) * 32 + kcol]; \
    if (ST) { GLDS(An, &SA[NB][0][lw]); GLDS(An + 16 * D_, &SA[NB][0][lw + 512]); } \
    asm volatile("s_waitcnt lgkmcnt(0)" ::: "memory");                         \
    __builtin_amdgcn_sched_barrier(0);                                         \
    MFMA16(af, 0);                                                             \
    _Pragma("unroll")                                                          \
    for (int mi_ = 0; mi_ < 4; ++mi_)                                          \
      af2[mi_] = *(const bf16x8*)&SA[DB][0][(wr * 128 + (4 + mi_) * 16 + r) * 32 + kcol]; \
    if (ST) { GLDS(An + 32, &SA[NB][1][lw]); GLDS(An + 32 + 16 * D_, &SA[NB][1][lw + 512]); } \
    asm volatile("s_waitcnt lgkmcnt(0)" ::: "memory");                         \
    __builtin_amdgcn_sched_barrier(0);                                         \
    MFMA16(af2, 4);                                                            \
    asm volatile("s_waitcnt vmcnt(" VM2 ")" ::: "memory");                     \
    __builtin_amdgcn_s_barrier();                                              \
    __builtin_amdgcn_sched_barrier(0);                                         \
    _Pragma("unroll")                                                          \
    for (int mi_ = 0; mi_ < 4; ++mi_)                                          \
      af[mi_] = *(const bf16x8*)&SA[DB][1][(wr * 128 + mi_ * 16 + r) * 32 + kcol]; \
    _Pragma("unroll")                                                          \
    for (int ni_ = 0; ni_ < 4; ++ni_)                                          \
      bf[ni_] = *(const bf16x8*)&SB[DB][1][(wc * 64 + ni_ * 16 + r) * 32 + kcol]; \
    if (ST) { GLDS(Bn, &SB[NB][0][lw]); GLDS(Bn + 16 * D_, &SB[NB][0][lw + 512]); } \
    asm volatile("s_waitcnt lgkmcnt(0)" ::: "memory");                         \
    __builtin_amdgcn_sched_barrier(0);                                         \
    MFMA16(af, 0);                                                             \
    _Pragma("unroll")                                                          \
    for (int mi_ = 0; mi_ < 4; ++mi_)                                          \
      af2[mi_] = *(const bf16x8*)&SA[DB][1][(wr * 128 + (4 + mi_) * 16 + r) * 32 + kcol]; \
    if (ST) { GLDS(Bn + 32, &SB[NB][1][lw]); GLDS(Bn + 32 + 16 * D_, &SB[NB][1][lw + 512]); } \
    asm volatile("s_waitcnt lgkmcnt(0)" ::: "memory");                         \
    __builtin_amdgcn_sched_barrier(0);                                         \
    MFMA16(af2, 4);                                                            \
  } while (0)

__global__ __launch_bounds__(512, 2) void k_gemm(const u16* __restrict__ X,
                                                 const u16* __restrict__ W,
                                                 u16* __restrict__ C) {
  __shared__ u16 SA[2][2][8192];
  __shared__ u16 SB[2][2][8192];
  int bid = blockIdx.x;
  int swzb = (bid & 7) * 96 + (bid >> 3);
  int tm = swzb / 12, tn = swzb - tm * 12;
  int m0 = tm << 8, n0 = tn << 8;
  int tid = threadIdx.x;
  int w = tid >> 6, l = tid & 63;
  int wr = w >> 2, wc = w & 3;
  int arow = w * 32 + (l >> 2);
  int csw = 8 * ((l & 3) ^ ((l >> 3) & 3));
  const u16* Ag = X + (size_t)(m0 + arow) * D_ + csw;
  const u16* Bg = W + (size_t)(n0 + arow) * D_ + csw;
  int lw = w * 1024;
  int r = l & 15, kq = l >> 4;
  int kcol = 8 * (kq ^ ((r >> 1) & 3));

  f32x4 acc[8][4];
  #pragma unroll
  for (int mi = 0; mi < 8; ++mi)
    #pragma unroll
    for (int ni = 0; ni < 4; ++ni)
      #pragma unroll
      for (int q = 0; q < 4; ++q) acc[mi][ni][q] = 0.f;

  bf16x8 af[4], af2[4], bf[4];

  GLDS(Ag,           &SA[0][0][lw]);  GLDS(Ag + 16 * D_,      &SA[0][0][lw + 512]);
  GLDS(Ag + 32,      &SA[0][1][lw]);  GLDS(Ag + 32 + 16 * D_, &SA[0][1][lw + 512]);
  GLDS(Bg,           &SB[0][0][lw]);  GLDS(Bg + 16 * D_,      &SB[0][0][lw + 512]);
  GLDS(Bg + 32,      &SB[0][1][lw]);  GLDS(Bg + 32 + 16 * D_, &SB[0][1][lw + 512]);

  for (int kt = 0; kt < NT_ - 1; ++kt) {
    int db = kt & 1, nb = db ^ 1;
    const u16* An = Ag + (size_t)(kt + 1) * 64;
    const u16* Bn = Bg + (size_t)(kt + 1) * 64;
    KTILE(db, nb, "2", "4", 1);
  }
  {
    const u16* An = Ag;
    const u16* Bn = Bg;
    KTILE(1, 0, "2", "0", 0);
  }

  int cr = (l >> 4) * 4, cc = l & 15;
  #pragma unroll
  for (int mi = 0; mi < 8; ++mi)
    #pragma unroll
    for (int ni = 0; ni < 4; ++ni)
      #pragma unroll
      for (int q = 0; q < 4; ++q) {
        int gm = m0 + wr * 128 + mi * 16 + cr + q;
        int gn = n0 + wc * 64 + ni * 16 + cc;
        C[(size_t)gm * NN + gn] = f2b(acc[mi][ni][q]);
      }
}

// K4: fused gk + chunk-sum, 64-t chunks, grid 1024. gk stored f16;
// ct accumulated from the f16-ROUNDED values (consistent with fused decay).
__global__ __launch_bounds__(256) void k_gkcs(const float* __restrict__ y,
                                              const float* __restrict__ w2,
                                              const float* __restrict__ gb,
                                              u16* __restrict__ gkh,
                                              float* __restrict__ ct) {
  __shared__ float yl[64][16];
  int blk = blockIdx.x;
  int cg = blk & 3, tc = (blk >> 2) & 63, b = blk >> 8;
  int tid = threadIdx.x;
  int c = cg * 256 + tid;
  {
    int row = tid >> 2, q = tid & 3;
    const float4* src = (const float4*)(y + (size_t)(b * T_ + tc * 64 + row) * 16 + q * 4);
    *(float4*)&yl[row][q * 4] = *src;
  }
  float w2r[16];
  {
    const float4* wsrc = (const float4*)(w2 + (size_t)c * 16);
    float4 q0 = wsrc[0], q1 = wsrc[1], q2 = wsrc[2], q3 = wsrc[3];
    w2r[0] = q0.x; w2r[1] = q0.y; w2r[2] = q0.z; w2r[3] = q0.w;
    w2r[4] = q1.x; w2r[5] = q1.y; w2r[6] = q1.z; w2r[7] = q1.w;
    w2r[8] = q2.x; w2r[9] = q2.y; w2r[10] = q2.z; w2r[11] = q2.w;
    w2r[12] = q3.x; w2r[13] = q3.y; w2r[14] = q3.z; w2r[15] = q3.w;
  }
  float gbr = gb[c];
  __syncthreads();
  float sum = 0.f;
  size_t rowbase = (size_t)(b * T_ + tc * 64) * HDK + c;
  for (int t = 0; t < 64; ++t) {
    const float4* yv4 = (const float4*)&yl[t][0];
    float4 y0 = yv4[0], y1 = yv4[1], y2 = yv4[2], y3 = yv4[3];
    float z = gbr;
    z = fmaf(y0.x, w2r[0], z);  z = fmaf(y0.y, w2r[1], z);
    z = fmaf(y0.z, w2r[2], z);  z = fmaf(y0.w, w2r[3], z);
    z = fmaf(y1.x, w2r[4], z);  z = fmaf(y1.y, w2r[5], z);
    z = fmaf(y1.z, w2r[6], z);  z = fmaf(y1.w, w2r[7], z);
    z = fmaf(y2.x, w2r[8], z);  z = fmaf(y2.y, w2r[9], z);
    z = fmaf(y2.z, w2r[10], z); z = fmaf(y2.w, w2r[11], z);
    z = fmaf(y3.x, w2r[12], z); z = fmaf(y3.y, w2r[13], z);
    z = fmaf(y3.z, w2r[14], z); z = fmaf(y3.w, w2r[15], z);
    float g = flogsig(z) * (1.f / 16.f);
    _Float16 hv = (_Float16)g;
    u16 bits; __builtin_memcpy(&bits, &hv, 2);
    gkh[rowbase + (size_t)t * HDK] = bits;
    sum += (float)hv;
  }
  ct[(size_t)(b * 64 + tc) * HDK + c] = sum;
}

// E2: scan 64 chunk sums -> exclusive offsets + totals. grid 16 (b x cg).
__global__ __launch_bounds__(256) void k_scan(const float* __restrict__ ct,
                                              float* __restrict__ co,
                                              float* __restrict__ gt) {
  int b = blockIdx.x >> 2, cg = blockIdx.x & 3;
  int c = cg * 256 + threadIdx.x;
  float run = 0.f;
  #pragma unroll 8
  for (int tc = 0; tc < 64; ++tc) {
    size_t idx = (size_t)(b * 64 + tc) * HDK + c;
    co[idx] = run;
    run += ct[idx];
  }
  gt[b * HDK + c] = run;
}

// K6 (NEW R16): fused decay + outer product. block = (s, h, b); 512 t/split.
// A-operand computed inline: A[t][c] = kv_k[t][c] * exp(g_total - G_t[c]),
// with G via co[64-chunk] + cross-atq LDS prefix (s8lds) + lane-local prefix.
// Decay for step KK computed at iteration KK-1 (s8 written pre-barrier1,
// read post-barrier1; slot reuse separated by barrier2 of prior iteration).
__global__ __launch_bounds__(256) void k_outer(const u16* __restrict__ gkh,
                                               const u16* __restrict__ kv,
                                               const float* __restrict__ co,
                                               const float* __restrict__ gt,
                                               float* __restrict__ part) {
  __shared__ u16 At[2][64][40];
  __shared__ u16 Vt[2][128][40];
  __shared__ float s8lds[2][64][4];
  int s = blockIdx.x, h = blockIdx.y, b = blockIdx.z;
  int tid = threadIdx.x;
  int w = tid >> 6, l = tid & 63;
  int adk = tid & 63, atq = tid >> 6;
  int vdv = tid & 127, vth = tid >> 7;
  int r = l & 15, q = l >> 4;
  int c = h * DK_ + adk;
  float g = gt[b * HDK + c];
  f32x4 acc[8];
  #pragma unroll
  for (int n = 0; n < 8; ++n)
    #pragma unroll
    for (int j = 0; j < 4; ++j) acc[n][j] = 0.f;

  union { int4 v[2]; u16 u[16]; } vbuf;
  union { int4 v; u16 u[8]; } kbuf;     // kv_k bf16 bits
  float gk8[8];                          // f16->f32 gate values for 8 t's
  union { int4 v; u16 u[8]; } abuf;     // decayed A (bf16) for WRITET
  float cobuf = 0.f, tot_prev = 0.f;

  // LOADT(KK): load gkh+kvk (8 each), v (16); co if KK even; s8 -> LDS slot KK&1
  #define LOADT(KK) do {                                                              \
      int t0_ = s * 512 + (KK) * 32;                                                  \
      _Pragma("unroll")                                                               \
      for (int i = 0; i < 8; ++i) {                                                   \
        size_t row_ = (size_t)(b * T_ + t0_ + atq * 8 + i);                           \
        u16 gb_ = gkh[row_ * HDK + c];                                                \
        _Float16 hv_; __builtin_memcpy(&hv_, &gb_, 2);                                \
        gk8[i] = (float)hv_;                                                          \
        kbuf.u[i] = kv[row_ * NN + c];                                                \
      }                                                                               \
      _Pragma("unroll")                                                               \
      for (int i = 0; i < 16; ++i)                                                    \
        vbuf.u[i] = kv[(size_t)(b * T_ + t0_ + vth * 16 + i) * NN + HDK + h * DV_ + vdv]; \
      if (((KK) & 1) == 0)                                                            \
        cobuf = co[(size_t)(b * 64 + s * 8 + ((KK) >> 1)) * HDK + c];                 \
      float s8_ = ((gk8[0] + gk8[1]) + (gk8[2] + gk8[3]))                             \
                + ((gk8[4] + gk8[5]) + (gk8[6] + gk8[7]));                            \
      s8lds[(KK) & 1][adk][atq] = s8_;                                                \
    } while (0)

  // DECAY(KK): after a barrier covering s8lds[KK&1] writes
  #define DECAY(KK) do {                                                              \
      float sv0 = s8lds[(KK) & 1][adk][0];                                            \
      float sv1 = s8lds[(KK) & 1][adk][1];                                            \
      float sv2 = s8lds[(KK) & 1][adk][2];                                            \
      float sv3 = s8lds[(KK) & 1][adk][3];                                            \
      float pre = (atq > 0 ? sv0 : 0.f) + (atq > 1 ? sv1 : 0.f) + (atq > 2 ? sv2 : 0.f); \
      float base;                                                                     \
      if (((KK) & 1) == 0) {                                                          \
        base = cobuf;                                                                 \
        tot_prev = base + ((sv0 + sv1) + (sv2 + sv3));                                \
      } else {                                                                        \
        base = tot_prev;                                                              \
      }                                                                               \
      float run_ = base + pre;                                                        \
      _Pragma("unroll")                                                               \
      for (int i = 0; i < 8; ++i) {                                                   \
        run_ += gk8[i];                                                               \
        float av_ = b2f(kbuf.u[i]) * fexp(g - run_);                                  \
        abuf.u[i] = f2b(av_);                                                         \
      }                                                                               \
    } while (0)

  #define WRITET(BF) do {                                                             \
      *(int4*)&At[BF][adk][atq * 8] = abuf.v;                                         \
      *(int4*)&Vt[BF][vdv][vth * 16] = vbuf.v[0];                                     \
      *(int4*)&Vt[BF][vdv][vth * 16 + 8] = vbuf.v[1];                                 \
    } while (0)

  // prologue: step 0
  LOADT(0);
  __syncthreads();   // s8lds[0] visible
  DECAY(0);
  WRITET(0);
  for (int kk = 0; kk < 16; ++kk) {
    int cur = kk & 1;
    if (kk < 15) LOADT(kk + 1);
    __syncthreads();                 // At/Vt[cur] + s8lds[(kk+1)&1] visible
    bf16x8 af = *(const bf16x8*)&At[cur][w * 16 + r][q * 8];
    #pragma unroll
    for (int n = 0; n < 8; ++n) {
      bf16x8 vf = *(const bf16x8*)&Vt[cur][n * 16 + r][q * 8];
      acc[n] = __builtin_amdgcn_mfma_f32_16x16x32_bf16(af, vf, acc[n], 0, 0, 0);
    }
    if (kk < 15) DECAY(kk + 1);
    __syncthreads();
    if (kk < 15) WRITET(1 - cur);
  }
  #undef LOADT
  #undef DECAY
  #undef WRITET

  float* dst = part + ((size_t)(b * H_ + h) * 8 + s) * (DK_ * DV_);
  #pragma unroll
  for (int n = 0; n < 8; ++n)
    #pragma unroll
    for (int j = 0; j < 4; ++j)
      dst[(w * 16 + q * 4 + j) * DV_ + n * 16 + r] = acc[n][j];
}

// K7: out = exp(g_total)*state + sum over 8 splits
__global__ __launch_bounds__(256) void k_final(const float* __restrict__ part,
                                               const float* __restrict__ gt,
                                               const float* __restrict__ st,
                                               float* __restrict__ out) {
  int i = blockIdx.x * 256 + threadIdx.x;
  int dv = i & 127, dk = (i >> 7) & 63, h = (i >> 13) & 15, b = i >> 17;
  size_t base = ((size_t)(b * H_ + h) * 8) * 8192 + dk * DV_ + dv;
  float s = 0.f;
  #pragma unroll
  for (int sp = 0; sp < 8; ++sp) s += part[base + (size_t)sp * 8192];
  float g = gt[b * HDK + h * DK_ + dk];
  out[i] = fexp(g) * st[i] + s;
}

extern "C" void kernel_launch(void* const* d_in, const int* in_sizes, int n_in,
                              void* d_out, int out_size, void* d_ws, size_t ws_size,
                              hipStream_t stream) {
  const float* hs = (const float*)d_in[0];
  const float* st = (const float*)d_in[1];
  const float* nw = (const float*)d_in[2];
  const float* kw = (const float*)d_in[3];
  const float* vw = (const float*)d_in[4];
  const float* w1 = (const float*)d_in[5];
  const float* w2 = (const float*)d_in[6];
  const float* gb = (const float*)d_in[7];
  float* out = (float*)d_out;
  char* ws = (char*)d_ws;

  u16*  Wb  = (u16*)(ws + 0);              // 12,582,912
  u16*  xb  = (u16*)(ws + 12582912);       // 67,108,864 (dead after gemm)
  float* y  = (float*)(ws + 79691776);     //  1,048,576
  u16*  kv  = (u16*)(ws + 80740352);       // 100,663,296
  u16*  gkh = (u16*)(ws + 181403648);      // 33,554,432 (f16)
  float* ct = (float*)(ws + 214958080);    //  1,048,576
  float* co = (float*)(ws + 216006656);    //  1,048,576
  float* gt = (float*)(ws + 217055232);    //     16,384
  float* part = (float*)(ws + 12582912);          // reuse xb region (16.8 MB)

  k_cvtw<<<dim3(3072), dim3(256), 0, stream>>>(kw, vw, Wb);
  k_rms<<<dim3(4096), dim3(256), 0, stream>>>(hs, nw, w1, xb, y);
  k_gemm<<<dim3(768), dim3(512), 0, stream>>>(xb, Wb, kv);
  k_gkcs<<<dim3(1024), dim3(256), 0, stream>>>(y, w2, gb, gkh, ct);
  k_scan<<<dim3(16), dim3(256), 0, stream>>>(ct, co, gt);
  k_outer<<<dim3(8, 16, 4), dim3(256), 0, stream>>>(gkh, kv, co, gt, part);
  k_final<<<dim3(2048), dim3(256), 0, stream>>>(part, gt, st, out);
}

// Round 17
// 351.290 us; speedup vs baseline: 1.2351x; 1.0082x over previous
//
#include <hip/hip_runtime.h>

#define B_ 4
#define T_ 4096
#define D_ 2048
#define H_ 16
#define DK_ 64
#define DV_ 128
#define HDK 1024
#define HDV 2048
#define NN 3072
#define MM 16384
#define NT_ 32  // D_/64 K-tiles (BK=64)

typedef unsigned short u16;
typedef unsigned int u32;
typedef __attribute__((ext_vector_type(8))) short bf16x8;
typedef __attribute__((ext_vector_type(4))) float f32x4;

typedef const __attribute__((address_space(1))) u16 gu16;
typedef __attribute__((address_space(3))) u16 lu16;

__device__ __forceinline__ float b2f(u16 u) {
  u32 x = ((u32)u) << 16; float f; __builtin_memcpy(&f, &x, 4); return f;
}
__device__ __forceinline__ u16 f2b(float f) {
  u32 x; __builtin_memcpy(&x, &f, 4);
  u32 r = x + 0x7FFFu + ((x >> 16) & 1u);
  return (u16)(r >> 16);
}
__device__ __forceinline__ float fexp(float x) { return exp2f(x * 1.44269504f); }
__device__ __forceinline__ float flogsig(float z) {
  float u = exp2f(-fabsf(z) * 1.44269504f);
  float l = log2f(1.f + u) * 0.69314718f;
  return fminf(z, 0.f) - l;
}

// K1: convert [k_w; v_w] (3072 x 2048 f32) -> bf16
__global__ __launch_bounds__(256) void k_cvtw(const float* __restrict__ kw,
                                              const float* __restrict__ vw,
                                              u16* __restrict__ Wb) {
  int i = blockIdx.x * 256 + threadIdx.x;
  size_t e = (size_t)i * 8;
  const float* src = (e < (size_t)HDK * D_) ? (kw + e) : (vw + (e - (size_t)HDK * D_));
  float4 f0 = ((const float4*)src)[0];
  float4 f1 = ((const float4*)src)[1];
  union { int4 v; u16 u[8]; } o;
  o.u[0] = f2b(f0.x); o.u[1] = f2b(f0.y); o.u[2] = f2b(f0.z); o.u[3] = f2b(f0.w);
  o.u[4] = f2b(f1.x); o.u[5] = f2b(f1.y); o.u[6] = f2b(f1.z); o.u[7] = f2b(f1.w);
  *(int4*)(Wb + e) = o.v;
}

// K2: RMSNorm -> x (bf16), and y = x @ gk_w1^T (f32, 16 per row). 4 rows/block.
// (R3/R5-proven version.)
__global__ __launch_bounds__(256) void k_rms(const float* __restrict__ hs,
                                             const float* __restrict__ nw,
                                             const float* __restrict__ w1,
                                             u16* __restrict__ xb,
                                             float* __restrict__ y) {
  int r0 = blockIdx.x * 4;
  int tid = threadIdx.x;
  int wv = tid >> 6, ln = tid & 63;
  __shared__ float red[4][4];
  __shared__ float ys[4][4][16];
  float x[4][8];
  float ssq[4];
  #pragma unroll
  for (int r = 0; r < 4; ++r) {
    const float4* hp = (const float4*)(hs + (size_t)(r0 + r) * D_);
    float4 a = hp[tid * 2], b = hp[tid * 2 + 1];
    x[r][0] = a.x; x[r][1] = a.y; x[r][2] = a.z; x[r][3] = a.w;
    x[r][4] = b.x; x[r][5] = b.y; x[r][6] = b.z; x[r][7] = b.w;
    float s = 0.f;
    #pragma unroll
    for (int i = 0; i < 8; ++i) s += x[r][i] * x[r][i];
    #pragma unroll
    for (int o = 32; o > 0; o >>= 1) s += __shfl_xor(s, o, 64);
    ssq[r] = s;
  }
  if (ln == 0) {
    #pragma unroll
    for (int r = 0; r < 4; ++r) red[wv][r] = ssq[r];
  }
  __syncthreads();
  const float4* np_ = (const float4*)nw;
  float4 n0 = np_[tid * 2], n1 = np_[tid * 2 + 1];
  float nwv[8] = {n0.x, n0.y, n0.z, n0.w, n1.x, n1.y, n1.z, n1.w};
  #pragma unroll
  for (int r = 0; r < 4; ++r) {
    float tot = red[0][r] + red[1][r] + red[2][r] + red[3][r];
    float inv = rsqrtf(tot * (1.f / D_) + 1e-5f);
    union { int4 v; u16 u[8]; } o;
    #pragma unroll
    for (int i = 0; i < 8; ++i) { x[r][i] = x[r][i] * inv * nwv[i]; o.u[i] = f2b(x[r][i]); }
    *(int4*)(xb + (size_t)(r0 + r) * D_ + tid * 8) = o.v;
  }
  float p[4][16];
  #pragma unroll
  for (int r = 0; r < 4; ++r)
    #pragma unroll
    for (int j = 0; j < 16; ++j) p[r][j] = 0.f;
  #pragma unroll
  for (int j = 0; j < 16; ++j) {
    const float4* wp = (const float4*)(w1 + (size_t)j * D_);
    float4 a = wp[tid * 2], b = wp[tid * 2 + 1];
    float wj[8] = {a.x, a.y, a.z, a.w, b.x, b.y, b.z, b.w};
    #pragma unroll
    for (int r = 0; r < 4; ++r) {
      float s = 0.f;
      #pragma unroll
      for (int i = 0; i < 8; ++i) s += x[r][i] * wj[i];
      p[r][j] = s;
    }
  }
  #pragma unroll
  for (int r = 0; r < 4; ++r)
    #pragma unroll
    for (int j = 0; j < 16; ++j) {
      float s = p[r][j];
      #pragma unroll
      for (int o = 32; o > 0; o >>= 1) s += __shfl_xor(s, o, 64);
      p[r][j] = s;
    }
  if (ln == 0) {
    for (int r = 0; r < 4; ++r)
      for (int j = 0; j < 16; ++j) ys[wv][r][j] = p[r][j];
  }
  __syncthreads();
  if (tid < 64) {
    int r = tid >> 4, j = tid & 15;
    y[(size_t)(r0 + r) * 16 + j] = ys[0][r][j] + ys[1][r][j] + ys[2][r][j] + ys[3][r][j];
  }
}

// K3: kv = x @ Wb^T. R11-proven verbatim: 256x256, 8 waves, BK=64,
// 2dbuf x 2kh, 4-phase KTILE, vmcnt(2)@P0 / vmcnt(4)@P2.
#define GLDS(SRC, DST) __builtin_amdgcn_global_load_lds((gu16*)(SRC), (lu16*)(DST), 16, 0, 0)

#define MFMA16(AF, MB) do {                                                    \
    __builtin_amdgcn_s_setprio(1);                                             \
    _Pragma("unroll")                                                          \
    for (int mi_ = 0; mi_ < 4; ++mi_)                                          \
      _Pragma("unroll")                                                        \
      for (int ni_ = 0; ni_ < 4; ++ni_)                                        \
        acc[(MB) + mi_][ni_] = __builtin_amdgcn_mfma_f32_16x16x32_bf16(        \
            AF[mi_], bf[ni_], acc[(MB) + mi_][ni_], 0, 0, 0);                  \
    __builtin_amdgcn_s_setprio(0);                                             \
    __builtin_amdgcn_sched_barrier(0);                                         \
  } while (0)

#define KTILE(DB, NB, VM0, VM2, ST) do {                                       \
    asm volatile("s_waitcnt vmcnt(" VM0 ")" ::: "memory");                     \
    __builtin_amdgcn_s_barrier();                                              \
    __builtin_amdgcn_sched_barrier(0);                                         \
    _Pragma("unroll")                                                          \
    for (int mi_ = 0; mi_ < 4; ++mi_)                                          \
      af[mi_] = *(const bf16x8*)&SA[DB][0][(wr * 128 + mi_ * 16 + r) * 32 + kcol]; \
    _Pragma("unroll")                                                          \
    for (int ni_ = 0; ni_ < 4; ++ni_)                                          \
      bf[ni_] = *(const bf16x8*)&SB[DB][0][(wc * 64 + ni_ * 16 + r) * 32 + kcol]; \
    if (ST) { GLDS(An, &SA[NB][0][lw]); GLDS(An + 16 * D_, &SA[NB][0][lw + 512]); } \
    asm volatile("s_waitcnt lgkmcnt(0)" ::: "memory");                         \
    __builtin_amdgcn_sched_barrier(0);                                         \
    MFMA16(af, 0);                                                             \
    _Pragma("unroll")                                                          \
    for (int mi_ = 0; mi_ < 4; ++mi_)                                          \
      af2[mi_] = *(const bf16x8*)&SA[DB][0][(wr * 128 + (4 + mi_) * 16 + r) * 32 + kcol]; \
    if (ST) { GLDS(An + 32, &SA[NB][1][lw]); GLDS(An + 32 + 16 * D_, &SA[NB][1][lw + 512]); } \
    asm volatile("s_waitcnt lgkmcnt(0)" ::: "memory");                         \
    __builtin_amdgcn_sched_barrier(0);                                         \
    MFMA16(af2, 4);                                                            \
    asm volatile("s_waitcnt vmcnt(" VM2 ")" ::: "memory");                     \
    __builtin_amdgcn_s_barrier();                                              \
    __builtin_amdgcn_sched_barrier(0);                                         \
    _Pragma("unroll")                                                          \
    for (int mi_ = 0; mi_ < 4; ++mi_)                                          \
      af[mi_] = *(const bf16x8*)&SA[DB][1][(wr * 128 + mi_ * 16 + r) * 32 + kcol]; \
    _Pragma("unroll")                                                          \
    for (int ni_ = 0; ni_ < 4; ++ni_)                                          \
      bf[ni_] = *(const bf16x8*)&SB[DB][1][(wc * 64 + ni_ * 16 + r) * 32 + kcol]; \
    if (ST) { GLDS(Bn, &SB[NB][0][lw]); GLDS(Bn + 16 * D_, &SB[NB][0][lw + 512]); } \
    asm volatile("s_waitcnt lgkmcnt(0)" ::: "memory");                         \
    __builtin_amdgcn_sched_barrier(0);                                         \
    MFMA16(af, 0);                                                             \
    _Pragma("unroll")                                                          \
    for (int mi_ = 0; mi_ < 4; ++mi_)                                          \
      af2[mi_] = *(const bf16x8*)&SA[DB][1][(wr * 128 + (4 + mi_) * 16 + r) * 32 + kcol]; \
    if (ST) { GLDS(Bn + 32, &SB[NB][1][lw]); GLDS(Bn + 32 + 16 * D_, &SB[NB][1][lw + 512]); } \
    asm volatile("s_waitcnt lgkmcnt(0)" ::: "memory");                         \
    __builtin_amdgcn_sched_barrier(0);                                         \
    MFMA16(af2, 4);                                                            \
  } while (0)

__global__ __launch_bounds__(512, 2) void k_gemm(const u16* __restrict__ X,
                                                 const u16* __restrict__ W,
                                                 u16* __restrict__ C) {
  __shared__ u16 SA[2][2][8192];
  __shared__ u16 SB[2][2][8192];
  int bid = blockIdx.x;
  int swzb = (bid & 7) * 96 + (bid >> 3);
  int tm = swzb / 12, tn = swzb - tm * 12;
  int m0 = tm << 8, n0 = tn << 8;
  int tid = threadIdx.x;
  int w = tid >> 6, l = tid & 63;
  int wr = w >> 2, wc = w & 3;
  int arow = w * 32 + (l >> 2);
  int csw = 8 * ((l & 3) ^ ((l >> 3) & 3));
  const u16* Ag = X + (size_t)(m0 + arow) * D_ + csw;
  const u16* Bg = W + (size_t)(n0 + arow) * D_ + csw;
  int lw = w * 1024;
  int r = l & 15, kq = l >> 4;
  int kcol = 8 * (kq ^ ((r >> 1) & 3));

  f32x4 acc[8][4];
  #pragma unroll
  for (int mi = 0; mi < 8; ++mi)
    #pragma unroll
    for (int ni = 0; ni < 4; ++ni)
      #pragma unroll
      for (int q = 0; q < 4; ++q) acc[mi][ni][q] = 0.f;

  bf16x8 af[4], af2[4], bf[4];

  GLDS(Ag,           &SA[0][0][lw]);  GLDS(Ag + 16 * D_,      &SA[0][0][lw + 512]);
  GLDS(Ag + 32,      &SA[0][1][lw]);  GLDS(Ag + 32 + 16 * D_, &SA[0][1][lw + 512]);
  GLDS(Bg,           &SB[0][0][lw]);  GLDS(Bg + 16 * D_,      &SB[0][0][lw + 512]);
  GLDS(Bg + 32,      &SB[0][1][lw]);  GLDS(Bg + 32 + 16 * D_, &SB[0][1][lw + 512]);

  for (int kt = 0; kt < NT_ - 1; ++kt) {
    int db = kt & 1, nb = db ^ 1;
    const u16* An = Ag + (size_t)(kt + 1) * 64;
    const u16* Bn = Bg + (size_t)(kt + 1) * 64;
    KTILE(db, nb, "2", "4", 1);
  }
  {
    const u16* An = Ag;
    const u16* Bn = Bg;
    KTILE(1, 0, "2", "0", 0);
  }

  int cr = (l >> 4) * 4, cc = l & 15;
  #pragma unroll
  for (int mi = 0; mi < 8; ++mi)
    #pragma unroll
    for (int ni = 0; ni < 4; ++ni)
      #pragma unroll
      for (int q = 0; q < 4; ++q) {
        int gm = m0 + wr * 128 + mi * 16 + cr + q;
        int gn = n0 + wc * 64 + ni * 16 + cc;
        C[(size_t)gm * NN + gn] = f2b(acc[mi][ni][q]);
      }
}

// K4: fused gk + chunk-sum, 64-t chunks, grid 1024. gk stored f16;
// ct accumulated from the f16-ROUNDED values (consistent with fused decay).
__global__ __launch_bounds__(256) void k_gkcs(const float* __restrict__ y,
                                              const float* __restrict__ w2,
                                              const float* __restrict__ gb,
                                              u16* __restrict__ gkh,
                                              float* __restrict__ ct) {
  __shared__ float yl[64][16];
  int blk = blockIdx.x;
  int cg = blk & 3, tc = (blk >> 2) & 63, b = blk >> 8;
  int tid = threadIdx.x;
  int c = cg * 256 + tid;
  {
    int row = tid >> 2, q = tid & 3;
    const float4* src = (const float4*)(y + (size_t)(b * T_ + tc * 64 + row) * 16 + q * 4);
    *(float4*)&yl[row][q * 4] = *src;
  }
  float w2r[16];
  {
    const float4* wsrc = (const float4*)(w2 + (size_t)c * 16);
    float4 q0 = wsrc[0], q1 = wsrc[1], q2 = wsrc[2], q3 = wsrc[3];
    w2r[0] = q0.x; w2r[1] = q0.y; w2r[2] = q0.z; w2r[3] = q0.w;
    w2r[4] = q1.x; w2r[5] = q1.y; w2r[6] = q1.z; w2r[7] = q1.w;
    w2r[8] = q2.x; w2r[9] = q2.y; w2r[10] = q2.z; w2r[11] = q2.w;
    w2r[12] = q3.x; w2r[13] = q3.y; w2r[14] = q3.z; w2r[15] = q3.w;
  }
  float gbr = gb[c];
  __syncthreads();
  float sum = 0.f;
  size_t rowbase = (size_t)(b * T_ + tc * 64) * HDK + c;
  for (int t = 0; t < 64; ++t) {
    const float4* yv4 = (const float4*)&yl[t][0];
    float4 y0 = yv4[0], y1 = yv4[1], y2 = yv4[2], y3 = yv4[3];
    float z = gbr;
    z = fmaf(y0.x, w2r[0], z);  z = fmaf(y0.y, w2r[1], z);
    z = fmaf(y0.z, w2r[2], z);  z = fmaf(y0.w, w2r[3], z);
    z = fmaf(y1.x, w2r[4], z);  z = fmaf(y1.y, w2r[5], z);
    z = fmaf(y1.z, w2r[6], z);  z = fmaf(y1.w, w2r[7], z);
    z = fmaf(y2.x, w2r[8], z);  z = fmaf(y2.y, w2r[9], z);
    z = fmaf(y2.z, w2r[10], z); z = fmaf(y2.w, w2r[11], z);
    z = fmaf(y3.x, w2r[12], z); z = fmaf(y3.y, w2r[13], z);
    z = fmaf(y3.z, w2r[14], z); z = fmaf(y3.w, w2r[15], z);
    float g = flogsig(z) * (1.f / 16.f);
    _Float16 hv = (_Float16)g;
    u16 bits; __builtin_memcpy(&bits, &hv, 2);
    gkh[rowbase + (size_t)t * HDK] = bits;
    sum += (float)hv;
  }
  ct[(size_t)(b * 64 + tc) * HDK + c] = sum;
}

// E2 (R17): scan with ALL 64 loads hoisted before the serial chain
// (latency-bound kernel: one wait instead of 64). Same add order -> bit-identical.
__global__ __launch_bounds__(256) void k_scan(const float* __restrict__ ct,
                                              float* __restrict__ co,
                                              float* __restrict__ gt) {
  int b = blockIdx.x >> 2, cg = blockIdx.x & 3;
  int c = cg * 256 + threadIdx.x;
  float v[64];
  #pragma unroll
  for (int tc = 0; tc < 64; ++tc)
    v[tc] = ct[(size_t)(b * 64 + tc) * HDK + c];
  float run = 0.f;
  #pragma unroll
  for (int tc = 0; tc < 64; ++tc) {
    co[(size_t)(b * 64 + tc) * HDK + c] = run;
    run += v[tc];
  }
  gt[b * HDK + c] = run;
}

// K6: fused decay + outer product (R16-proven). block = (s, h, b); 512 t/split.
__global__ __launch_bounds__(256) void k_outer(const u16* __restrict__ gkh,
                                               const u16* __restrict__ kv,
                                               const float* __restrict__ co,
                                               const float* __restrict__ gt,
                                               float* __restrict__ part) {
  __shared__ u16 At[2][64][40];
  __shared__ u16 Vt[2][128][40];
  __shared__ float s8lds[2][64][4];
  int s = blockIdx.x, h = blockIdx.y, b = blockIdx.z;
  int tid = threadIdx.x;
  int w = tid >> 6, l = tid & 63;
  int adk = tid & 63, atq = tid >> 6;
  int vdv = tid & 127, vth = tid >> 7;
  int r = l & 15, q = l >> 4;
  int c = h * DK_ + adk;
  float g = gt[b * HDK + c];
  f32x4 acc[8];
  #pragma unroll
  for (int n = 0; n < 8; ++n)
    #pragma unroll
    for (int j = 0; j < 4; ++j) acc[n][j] = 0.f;

  union { int4 v[2]; u16 u[16]; } vbuf;
  union { int4 v; u16 u[8]; } kbuf;
  float gk8[8];
  union { int4 v; u16 u[8]; } abuf;
  float cobuf = 0.f, tot_prev = 0.f;

  #define LOADT(KK) do {                                                              \
      int t0_ = s * 512 + (KK) * 32;                                                  \
      _Pragma("unroll")                                                               \
      for (int i = 0; i < 8; ++i) {                                                   \
        size_t row_ = (size_t)(b * T_ + t0_ + atq * 8 + i);                           \
        u16 gb_ = gkh[row_ * HDK + c];                                                \
        _Float16 hv_; __builtin_memcpy(&hv_, &gb_, 2);                                \
        gk8[i] = (float)hv_;                                                          \
        kbuf.u[i] = kv[row_ * NN + c];                                                \
      }                                                                               \
      _Pragma("unroll")                                                               \
      for (int i = 0; i < 16; ++i)                                                    \
        vbuf.u[i] = kv[(size_t)(b * T_ + t0_ + vth * 16 + i) * NN + HDK + h * DV_ + vdv]; \
      if (((KK) & 1) == 0)                                                            \
        cobuf = co[(size_t)(b * 64 + s * 8 + ((KK) >> 1)) * HDK + c];                 \
      float s8_ = ((gk8[0] + gk8[1]) + (gk8[2] + gk8[3]))                             \
                + ((gk8[4] + gk8[5]) + (gk8[6] + gk8[7]));                            \
      s8lds[(KK) & 1][adk][atq] = s8_;                                                \
    } while (0)

  #define DECAY(KK) do {                                                              \
      float sv0 = s8lds[(KK) & 1][adk][0];                                            \
      float sv1 = s8lds[(KK) & 1][adk][1];                                            \
      float sv2 = s8lds[(KK) & 1][adk][2];                                            \
      float sv3 = s8lds[(KK) & 1][adk][3];                                            \
      float pre = (atq > 0 ? sv0 : 0.f) + (atq > 1 ? sv1 : 0.f) + (atq > 2 ? sv2 : 0.f); \
      float base;                                                                     \
      if (((KK) & 1) == 0) {                                                          \
        base = cobuf;                                                                 \
        tot_prev = base + ((sv0 + sv1) + (sv2 + sv3));                                \
      } else {                                                                        \
        base = tot_prev;                                                              \
      }                                                                               \
      float run_ = base + pre;                                                        \
      _Pragma("unroll")                                                               \
      for (int i = 0; i < 8; ++i) {                                                   \
        run_ += gk8[i];                                                               \
        float av_ = b2f(kbuf.u[i]) * fexp(g - run_);                                  \
        abuf.u[i] = f2b(av_);                                                         \
      }                                                                               \
    } while (0)

  #define WRITET(BF) do {                                                             \
      *(int4*)&At[BF][adk][atq * 8] = abuf.v;                                         \
      *(int4*)&Vt[BF][vdv][vth * 16] = vbuf.v[0];                                     \
      *(int4*)&Vt[BF][vdv][vth * 16 + 8] = vbuf.v[1];                                 \
    } while (0)

  LOADT(0);
  __syncthreads();
  DECAY(0);
  WRITET(0);
  for (int kk = 0; kk < 16; ++kk) {
    int cur = kk & 1;
    if (kk < 15) LOADT(kk + 1);
    __syncthreads();
    bf16x8 af = *(const bf16x8*)&At[cur][w * 16 + r][q * 8];
    #pragma unroll
    for (int n = 0; n < 8; ++n) {
      bf16x8 vf = *(const bf16x8*)&Vt[cur][n * 16 + r][q * 8];
      acc[n] = __builtin_amdgcn_mfma_f32_16x16x32_bf16(af, vf, acc[n], 0, 0, 0);
    }
    if (kk < 15) DECAY(kk + 1);
    __syncthreads();
    if (kk < 15) WRITET(1 - cur);
  }
  #undef LOADT
  #undef DECAY
  #undef WRITET

  float* dst = part + ((size_t)(b * H_ + h) * 8 + s) * (DK_ * DV_);
  #pragma unroll
  for (int n = 0; n < 8; ++n)
    #pragma unroll
    for (int j = 0; j < 4; ++j)
      dst[(w * 16 + q * 4 + j) * DV_ + n * 16 + r] = acc[n][j];
}

// K7 (R17): out = exp(g_total)*state + sum over 8 splits. float4-vectorized.
__global__ __launch_bounds__(256) void k_final(const float* __restrict__ part,
                                               const float* __restrict__ gt,
                                               const float* __restrict__ st,
                                               float* __restrict__ out) {
  int i4 = blockIdx.x * 256 + threadIdx.x;   // grid 512: 131072 quads
  int i = i4 * 4;
  int dv = i & 127, dk = (i >> 7) & 63, h = (i >> 13) & 15, b = i >> 17;
  size_t base = ((size_t)(b * H_ + h) * 8) * 8192 + dk * DV_ + dv;
  float4 sacc = {0.f, 0.f, 0.f, 0.f};
  #pragma unroll
  for (int sp = 0; sp < 8; ++sp) {
    float4 pv = *(const float4*)&part[base + (size_t)sp * 8192];
    sacc.x += pv.x; sacc.y += pv.y; sacc.z += pv.z; sacc.w += pv.w;
  }
  float eg = fexp(gt[b * HDK + h * DK_ + dk]);
  float4 stv = *(const float4*)&st[i];
  float4 o;
  o.x = eg * stv.x + sacc.x;
  o.y = eg * stv.y + sacc.y;
  o.z = eg * stv.z + sacc.z;
  o.w = eg * stv.w + sacc.w;
  *(float4*)&out[i] = o;
}

extern "C" void kernel_launch(void* const* d_in, const int* in_sizes, int n_in,
                              void* d_out, int out_size, void* d_ws, size_t ws_size,
                              hipStream_t stream) {
  const float* hs = (const float*)d_in[0];
  const float* st = (const float*)d_in[1];
  const float* nw = (const float*)d_in[2];
  const float* kw = (const float*)d_in[3];
  const float* vw = (const float*)d_in[4];
  const float* w1 = (const float*)d_in[5];
  const float* w2 = (const float*)d_in[6];
  const float* gb = (const float*)d_in[7];
  float* out = (float*)d_out;
  char* ws = (char*)d_ws;

  u16*  Wb  = (u16*)(ws + 0);              // 12,582,912
  u16*  xb  = (u16*)(ws + 12582912);       // 67,108,864 (dead after gemm)
  float* y  = (float*)(ws + 79691776);     //  1,048,576
  u16*  kv  = (u16*)(ws + 80740352);       // 100,663,296
  u16*  gkh = (u16*)(ws + 181403648);      // 33,554,432 (f16)
  float* ct = (float*)(ws + 214958080);    //  1,048,576
  float* co = (float*)(ws + 216006656);    //  1,048,576
  float* gt = (float*)(ws + 217055232);    //     16,384
  float* part = (float*)(ws + 12582912);          // reuse xb region (16.8 MB)

  k_cvtw<<<dim3(3072), dim3(256), 0, stream>>>(kw, vw, Wb);
  k_rms<<<dim3(4096), dim3(256), 0, stream>>>(hs, nw, w1, xb, y);
  k_gemm<<<dim3(768), dim3(512), 0, stream>>>(xb, Wb, kv);
  k_gkcs<<<dim3(1024), dim3(256), 0, stream>>>(y, w2, gb, gkh, ct);
  k_scan<<<dim3(16), dim3(256), 0, stream>>>(ct, co, gt);
  k_outer<<<dim3(8, 16, 4), dim3(256), 0, stream>>>(gkh, kv, co, gt, part);
  k_final<<<dim3(512), dim3(256), 0, stream>>>(part, gt, st, out);
}

// Round 18
// 351.018 us; speedup vs baseline: 1.2361x; 1.0008x over previous
//
#include <hip/hip_runtime.h>

#define B_ 4
#define T_ 4096
#define D_ 2048
#define H_ 16
#define DK_ 64
#define DV_ 128
#define HDK 1024
#define HDV 2048
#define NN 3072
#define MM 16384
#define NT_ 32  // D_/64 K-tiles (BK=64)

typedef unsigned short u16;
typedef unsigned int u32;
typedef __attribute__((ext_vector_type(8))) short bf16x8;
typedef __attribute__((ext_vector_type(4))) float f32x4;

typedef const __attribute__((address_space(1))) u16 gu16;
typedef __attribute__((address_space(3))) u16 lu16;

__device__ __forceinline__ float b2f(u16 u) {
  u32 x = ((u32)u) << 16; float f; __builtin_memcpy(&f, &x, 4); return f;
}
__device__ __forceinline__ u16 f2b(float f) {
  u32 x; __builtin_memcpy(&x, &f, 4);
  u32 r = x + 0x7FFFu + ((x >> 16) & 1u);
  return (u16)(r >> 16);
}
__device__ __forceinline__ float fexp(float x) { return exp2f(x * 1.44269504f); }
__device__ __forceinline__ float flogsig(float z) {
  float u = exp2f(-fabsf(z) * 1.44269504f);
  float l = log2f(1.f + u) * 0.69314718f;
  return fminf(z, 0.f) - l;
}

// K1: convert [k_w; v_w] (3072 x 2048 f32) -> bf16
__global__ __launch_bounds__(256) void k_cvtw(const float* __restrict__ kw,
                                              const float* __restrict__ vw,
                                              u16* __restrict__ Wb) {
  int i = blockIdx.x * 256 + threadIdx.x;
  size_t e = (size_t)i * 8;
  const float* src = (e < (size_t)HDK * D_) ? (kw + e) : (vw + (e - (size_t)HDK * D_));
  float4 f0 = ((const float4*)src)[0];
  float4 f1 = ((const float4*)src)[1];
  union { int4 v; u16 u[8]; } o;
  o.u[0] = f2b(f0.x); o.u[1] = f2b(f0.y); o.u[2] = f2b(f0.z); o.u[3] = f2b(f0.w);
  o.u[4] = f2b(f1.x); o.u[5] = f2b(f1.y); o.u[6] = f2b(f1.z); o.u[7] = f2b(f1.w);
  *(int4*)(Wb + e) = o.v;
}

// K2: RMSNorm -> x (bf16), and y = x @ gk_w1^T (f32, 16 per row). 4 rows/block.
// (R3/R5-proven version.)
__global__ __launch_bounds__(256) void k_rms(const float* __restrict__ hs,
                                             const float* __restrict__ nw,
                                             const float* __restrict__ w1,
                                             u16* __restrict__ xb,
                                             float* __restrict__ y) {
  int r0 = blockIdx.x * 4;
  int tid = threadIdx.x;
  int wv = tid >> 6, ln = tid & 63;
  __shared__ float red[4][4];
  __shared__ float ys[4][4][16];
  float x[4][8];
  float ssq[4];
  #pragma unroll
  for (int r = 0; r < 4; ++r) {
    const float4* hp = (const float4*)(hs + (size_t)(r0 + r) * D_);
    float4 a = hp[tid * 2], b = hp[tid * 2 + 1];
    x[r][0] = a.x; x[r][1] = a.y; x[r][2] = a.z; x[r][3] = a.w;
    x[r][4] = b.x; x[r][5] = b.y; x[r][6] = b.z; x[r][7] = b.w;
    float s = 0.f;
    #pragma unroll
    for (int i = 0; i < 8; ++i) s += x[r][i] * x[r][i];
    #pragma unroll
    for (int o = 32; o > 0; o >>= 1) s += __shfl_xor(s, o, 64);
    ssq[r] = s;
  }
  if (ln == 0) {
    #pragma unroll
    for (int r = 0; r < 4; ++r) red[wv][r] = ssq[r];
  }
  __syncthreads();
  const float4* np_ = (const float4*)nw;
  float4 n0 = np_[tid * 2], n1 = np_[tid * 2 + 1];
  float nwv[8] = {n0.x, n0.y, n0.z, n0.w, n1.x, n1.y, n1.z, n1.w};
  #pragma unroll
  for (int r = 0; r < 4; ++r) {
    float tot = red[0][r] + red[1][r] + red[2][r] + red[3][r];
    float inv = rsqrtf(tot * (1.f / D_) + 1e-5f);
    union { int4 v; u16 u[8]; } o;
    #pragma unroll
    for (int i = 0; i < 8; ++i) { x[r][i] = x[r][i] * inv * nwv[i]; o.u[i] = f2b(x[r][i]); }
    *(int4*)(xb + (size_t)(r0 + r) * D_ + tid * 8) = o.v;
  }
  float p[4][16];
  #pragma unroll
  for (int r = 0; r < 4; ++r)
    #pragma unroll
    for (int j = 0; j < 16; ++j) p[r][j] = 0.f;
  #pragma unroll
  for (int j = 0; j < 16; ++j) {
    const float4* wp = (const float4*)(w1 + (size_t)j * D_);
    float4 a = wp[tid * 2], b = wp[tid * 2 + 1];
    float wj[8] = {a.x, a.y, a.z, a.w, b.x, b.y, b.z, b.w};
    #pragma unroll
    for (int r = 0; r < 4; ++r) {
      float s = 0.f;
      #pragma unroll
      for (int i = 0; i < 8; ++i) s += x[r][i] * wj[i];
      p[r][j] = s;
    }
  }
  #pragma unroll
  for (int r = 0; r < 4; ++r)
    #pragma unroll
    for (int j = 0; j < 16; ++j) {
      float s = p[r][j];
      #pragma unroll
      for (int o = 32; o > 0; o >>= 1) s += __shfl_xor(s, o, 64);
      p[r][j] = s;
    }
  if (ln == 0) {
    for (int r = 0; r < 4; ++r)
      for (int j = 0; j < 16; ++j) ys[wv][r][j] = p[r][j];
  }
  __syncthreads();
  if (tid < 64) {
    int r = tid >> 4, j = tid & 15;
    y[(size_t)(r0 + r) * 16 + j] = ys[0][r][j] + ys[1][r][j] + ys[2][r][j] + ys[3][r][j];
  }
}

// K3: kv = x @ Wb^T. R11-proven verbatim: 256x256, 8 waves, BK=64,
// 2dbuf x 2kh, 4-phase KTILE, vmcnt(2)@P0 / vmcnt(4)@P2.
#define GLDS(SRC, DST) __builtin_amdgcn_global_load_lds((gu16*)(SRC), (lu16*)(DST), 16, 0, 0)

#define MFMA16(AF, MB) do {                                                    \
    __builtin_amdgcn_s_setprio(1);                                             \
    _Pragma("unroll")                                                          \
    for (int mi_ = 0; mi_ < 4; ++mi_)                                          \
      _Pragma("unroll")                                                        \
      for (int ni_ = 0; ni_ < 4; ++ni_)                                        \
        acc[(MB) + mi_][ni_] = __builtin_amdgcn_mfma_f32_16x16x32_bf16(        \
            AF[mi_], bf[ni_], acc[(MB) + mi_][ni_], 0, 0, 0);                  \
    __builtin_amdgcn_s_setprio(0);                                             \
    __builtin_amdgcn_sched_barrier(0);                                         \
  } while (0)

#define KTILE(DB, NB, VM0, VM2, ST) do {                                       \
    asm volatile("s_waitcnt vmcnt(" VM0 ")" ::: "memory");                     \
    __builtin_amdgcn_s_barrier();                                              \
    __builtin_amdgcn_sched_barrier(0);                                         \
    _Pragma("unroll")                                                          \
    for (int mi_ = 0; mi_ < 4; ++mi_)                                          \
      af[mi_] = *(const bf16x8*)&SA[DB][0][(wr * 128 + mi_ * 16 + r) * 32 + kcol]; \
    _Pragma("unroll")                                                          \
    for (int ni_ = 0; ni_ < 4; ++ni_)                                          \
      bf[ni_] = *(const bf16x8*)&SB[DB][0][(wc * 64 + ni_ * 16 + r) * 32 + kcol]; \
    if (ST) { GLDS(An, &SA[NB][0][lw]); GLDS(An + 16 * D_, &SA[NB][0][lw + 512]); } \
    asm volatile("s_waitcnt lgkmcnt(0)" ::: "memory");                         \
    __builtin_amdgcn_sched_barrier(0);                                         \
    MFMA16(af, 0);                                                             \
    _Pragma("unroll")                                                          \
    for (int mi_ = 0; mi_ < 4; ++mi_)                                          \
      af2[mi_] = *(const bf16x8*)&SA[DB][0][(wr * 128 + (4 + mi_) * 16 + r) * 32 + kcol]; \
    if (ST) { GLDS(An + 32, &SA[NB][1][lw]); GLDS(An + 32 + 16 * D_, &SA[NB][1][lw + 512]); } \
    asm volatile("s_waitcnt lgkmcnt(0)" ::: "memory");                         \
    __builtin_amdgcn_sched_barrier(0);                                         \
    MFMA16(af2, 4);                                                            \
    asm volatile("s_waitcnt vmcnt(" VM2 ")" ::: "memory");                     \
    __builtin_amdgcn_s_barrier();                                              \
    __builtin_amdgcn_sched_barrier(0);                                         \
    _Pragma("unroll")                                                          \
    for (int mi_ = 0; mi_ < 4; ++mi_)                                          \
      af[mi_] = *(const bf16x8*)&SA[DB][1][(wr * 128 + mi_ * 16 + r) * 32 + kcol]; \
    _Pragma("unroll")                                                          \
    for (int ni_ = 0; ni_ < 4; ++ni_)                                          \
      bf[ni_] = *(const bf16x8*)&SB[DB][1][(wc * 64 + ni_ * 16 + r) * 32 + kcol]; \
    if (ST) { GLDS(Bn, &SB[NB][0][lw]); GLDS(Bn + 16 * D_, &SB[NB][0][lw + 512]); } \
    asm volatile("s_waitcnt lgkmcnt(0)" ::: "memory");                         \
    __builtin_amdgcn_sched_barrier(0);                                         \
    MFMA16(af, 0);                                                             \
    _Pragma("unroll")                                                          \
    for (int mi_ = 0; mi_ < 4; ++mi_)                                          \
      af2[mi_] = *(const bf16x8*)&SA[DB][1][(wr * 128 + (4 + mi_) * 16 + r) * 32 + kcol]; \
    if (ST) { GLDS(Bn + 32, &SB[NB][1][lw]); GLDS(Bn + 32 + 16 * D_, &SB[NB][1][lw + 512]); } \
    asm volatile("s_waitcnt lgkmcnt(0)" ::: "memory");                         \
    __builtin_amdgcn_sched_barrier(0);                                         \
    MFMA16(af2, 4);                                                            \
  } while (0)

__global__ __launch_bounds__(512, 2) void k_gemm(const u16* __restrict__ X,
                                                 const u16* __restrict__ W,
                                                 u16* __restrict__ C) {
  __shared__ u16 SA[2][2][8192];
  __shared__ u16 SB[2][2][8192];
  int bid = blockIdx.x;
  int swzb = (bid & 7) * 96 + (bid >> 3);
  int tm = swzb / 12, tn = swzb - tm * 12;
  int m0 = tm << 8, n0 = tn << 8;
  int tid = threadIdx.x;
  int w = tid >> 6, l = tid & 63;
  int wr = w >> 2, wc = w & 3;
  int arow = w * 32 + (l >> 2);
  int csw = 8 * ((l & 3) ^ ((l >> 3) & 3));
  const u16* Ag = X + (size_t)(m0 + arow) * D_ + csw;
  const u16* Bg = W + (size_t)(n0 + arow) * D_ + csw;
  int lw = w * 1024;
  int r = l & 15, kq = l >> 4;
  int kcol = 8 * (kq ^ ((r >> 1) & 3));

  f32x4 acc[8][4];
  #pragma unroll
  for (int mi = 0; mi < 8; ++mi)
    #pragma unroll
    for (int ni = 0; ni < 4; ++ni)
      #pragma unroll
      for (int q = 0; q < 4; ++q) acc[mi][ni][q] = 0.f;

  bf16x8 af[4], af2[4], bf[4];

  GLDS(Ag,           &SA[0][0][lw]);  GLDS(Ag + 16 * D_,      &SA[0][0][lw + 512]);
  GLDS(Ag + 32,      &SA[0][1][lw]);  GLDS(Ag + 32 + 16 * D_, &SA[0][1][lw + 512]);
  GLDS(Bg,           &SB[0][0][lw]);  GLDS(Bg + 16 * D_,      &SB[0][0][lw + 512]);
  GLDS(Bg + 32,      &SB[0][1][lw]);  GLDS(Bg + 32 + 16 * D_, &SB[0][1][lw + 512]);

  for (int kt = 0; kt < NT_ - 1; ++kt) {
    int db = kt & 1, nb = db ^ 1;
    const u16* An = Ag + (size_t)(kt + 1) * 64;
    const u16* Bn = Bg + (size_t)(kt + 1) * 64;
    KTILE(db, nb, "2", "4", 1);
  }
  {
    const u16* An = Ag;
    const u16* Bn = Bg;
    KTILE(1, 0, "2", "0", 0);
  }

  int cr = (l >> 4) * 4, cc = l & 15;
  #pragma unroll
  for (int mi = 0; mi < 8; ++mi)
    #pragma unroll
    for (int ni = 0; ni < 4; ++ni)
      #pragma unroll
      for (int q = 0; q < 4; ++q) {
        int gm = m0 + wr * 128 + mi * 16 + cr + q;
        int gn = n0 + wc * 64 + ni * 16 + cc;
        C[(size_t)gm * NN + gn] = f2b(acc[mi][ni][q]);
      }
}

// K4: fused gk + chunk-sum, 64-t chunks, grid 1024. gk stored f16;
// ct accumulated from the f16-ROUNDED values (consistent with fused decay).
__global__ __launch_bounds__(256) void k_gkcs(const float* __restrict__ y,
                                              const float* __restrict__ w2,
                                              const float* __restrict__ gb,
                                              u16* __restrict__ gkh,
                                              float* __restrict__ ct) {
  __shared__ float yl[64][16];
  int blk = blockIdx.x;
  int cg = blk & 3, tc = (blk >> 2) & 63, b = blk >> 8;
  int tid = threadIdx.x;
  int c = cg * 256 + tid;
  {
    int row = tid >> 2, q = tid & 3;
    const float4* src = (const float4*)(y + (size_t)(b * T_ + tc * 64 + row) * 16 + q * 4);
    *(float4*)&yl[row][q * 4] = *src;
  }
  float w2r[16];
  {
    const float4* wsrc = (const float4*)(w2 + (size_t)c * 16);
    float4 q0 = wsrc[0], q1 = wsrc[1], q2 = wsrc[2], q3 = wsrc[3];
    w2r[0] = q0.x; w2r[1] = q0.y; w2r[2] = q0.z; w2r[3] = q0.w;
    w2r[4] = q1.x; w2r[5] = q1.y; w2r[6] = q1.z; w2r[7] = q1.w;
    w2r[8] = q2.x; w2r[9] = q2.y; w2r[10] = q2.z; w2r[11] = q2.w;
    w2r[12] = q3.x; w2r[13] = q3.y; w2r[14] = q3.z; w2r[15] = q3.w;
  }
  float gbr = gb[c];
  __syncthreads();
  float sum = 0.f;
  size_t rowbase = (size_t)(b * T_ + tc * 64) * HDK + c;
  for (int t = 0; t < 64; ++t) {
    const float4* yv4 = (const float4*)&yl[t][0];
    float4 y0 = yv4[0], y1 = yv4[1], y2 = yv4[2], y3 = yv4[3];
    float z = gbr;
    z = fmaf(y0.x, w2r[0], z);  z = fmaf(y0.y, w2r[1], z);
    z = fmaf(y0.z, w2r[2], z);  z = fmaf(y0.w, w2r[3], z);
    z = fmaf(y1.x, w2r[4], z);  z = fmaf(y1.y, w2r[5], z);
    z = fmaf(y1.z, w2r[6], z);  z = fmaf(y1.w, w2r[7], z);
    z = fmaf(y2.x, w2r[8], z);  z = fmaf(y2.y, w2r[9], z);
    z = fmaf(y2.z, w2r[10], z); z = fmaf(y2.w, w2r[11], z);
    z = fmaf(y3.x, w2r[12], z); z = fmaf(y3.y, w2r[13], z);
    z = fmaf(y3.z, w2r[14], z); z = fmaf(y3.w, w2r[15], z);
    float g = flogsig(z) * (1.f / 16.f);
    _Float16 hv = (_Float16)g;
    u16 bits; __builtin_memcpy(&bits, &hv, 2);
    gkh[rowbase + (size_t)t * HDK] = bits;
    sum += (float)hv;
  }
  ct[(size_t)(b * 64 + tc) * HDK + c] = sum;
}

// E2 (R18): scan with tc split in 2 halves per c (512 threads; 2x in-flight
// loads/stores vs R17). half0 total -> LDS -> half1 base. Rounding differs
// from the single-chain version by ~1 ulp (negligible vs f16 gate storage).
__global__ __launch_bounds__(512) void k_scan(const float* __restrict__ ct,
                                              float* __restrict__ co,
                                              float* __restrict__ gt) {
  int b = blockIdx.x >> 2, cg = blockIdx.x & 3;
  int tid = threadIdx.x;
  int c = cg * 256 + (tid & 255);
  int half = tid >> 8;
  __shared__ float s0l[256];
  float v[32];
  #pragma unroll
  for (int t = 0; t < 32; ++t)
    v[t] = ct[(size_t)(b * 64 + half * 32 + t) * HDK + c];
  if (half == 0) {
    float tot = 0.f;
    #pragma unroll
    for (int t = 0; t < 32; ++t) tot += v[t];
    s0l[tid & 255] = tot;
  }
  __syncthreads();
  float run = (half == 0) ? 0.f : s0l[tid & 255];
  #pragma unroll
  for (int t = 0; t < 32; ++t) {
    co[(size_t)(b * 64 + half * 32 + t) * HDK + c] = run;
    run += v[t];
  }
  if (half == 1) gt[b * HDK + c] = run;
}

// K6: fused decay + outer product (R16-proven). block = (s, h, b); 512 t/split.
__global__ __launch_bounds__(256) void k_outer(const u16* __restrict__ gkh,
                                               const u16* __restrict__ kv,
                                               const float* __restrict__ co,
                                               const float* __restrict__ gt,
                                               float* __restrict__ part) {
  __shared__ u16 At[2][64][40];
  __shared__ u16 Vt[2][128][40];
  __shared__ float s8lds[2][64][4];
  int s = blockIdx.x, h = blockIdx.y, b = blockIdx.z;
  int tid = threadIdx.x;
  int w = tid >> 6, l = tid & 63;
  int adk = tid & 63, atq = tid >> 6;
  int vdv = tid & 127, vth = tid >> 7;
  int r = l & 15, q = l >> 4;
  int c = h * DK_ + adk;
  float g = gt[b * HDK + c];
  f32x4 acc[8];
  #pragma unroll
  for (int n = 0; n < 8; ++n)
    #pragma unroll
    for (int j = 0; j < 4; ++j) acc[n][j] = 0.f;

  union { int4 v[2]; u16 u[16]; } vbuf;
  union { int4 v; u16 u[8]; } kbuf;
  float gk8[8];
  union { int4 v; u16 u[8]; } abuf;
  float cobuf = 0.f, tot_prev = 0.f;

  #define LOADT(KK) do {                                                              \
      int t0_ = s * 512 + (KK) * 32;                                                  \
      _Pragma("unroll")                                                               \
      for (int i = 0; i < 8; ++i) {                                                   \
        size_t row_ = (size_t)(b * T_ + t0_ + atq * 8 + i);                           \
        u16 gb_ = gkh[row_ * HDK + c];                                                \
        _Float16 hv_; __builtin_memcpy(&hv_, &gb_, 2);                                \
        gk8[i] = (float)hv_;                                                          \
        kbuf.u[i] = kv[row_ * NN + c];                                                \
      }                                                                               \
      _Pragma("unroll")                                                               \
      for (int i = 0; i < 16; ++i)                                                    \
        vbuf.u[i] = kv[(size_t)(b * T_ + t0_ + vth * 16 + i) * NN + HDK + h * DV_ + vdv]; \
      if (((KK) & 1) == 0)                                                            \
        cobuf = co[(size_t)(b * 64 + s * 8 + ((KK) >> 1)) * HDK + c];                 \
      float s8_ = ((gk8[0] + gk8[1]) + (gk8[2] + gk8[3]))                             \
                + ((gk8[4] + gk8[5]) + (gk8[6] + gk8[7]));                            \
      s8lds[(KK) & 1][adk][atq] = s8_;                                                \
    } while (0)

  #define DECAY(KK) do {                                                              \
      float sv0 = s8lds[(KK) & 1][adk][0];                                            \
      float sv1 = s8lds[(KK) & 1][adk][1];                                            \
      float sv2 = s8lds[(KK) & 1][adk][2];                                            \
      float sv3 = s8lds[(KK) & 1][adk][3];                                            \
      float pre = (atq > 0 ? sv0 : 0.f) + (atq > 1 ? sv1 : 0.f) + (atq > 2 ? sv2 : 0.f); \
      float base;                                                                     \
      if (((KK) & 1) == 0) {                                                          \
        base = cobuf;                                                                 \
        tot_prev = base + ((sv0 + sv1) + (sv2 + sv3));                                \
      } else {                                                                        \
        base = tot_prev;                                                              \
      }                                                                               \
      float run_ = base + pre;                                                        \
      _Pragma("unroll")                                                               \
      for (int i = 0; i < 8; ++i) {                                                   \
        run_ += gk8[i];                                                               \
        float av_ = b2f(kbuf.u[i]) * fexp(g - run_);                                  \
        abuf.u[i] = f2b(av_);                                                         \
      }                                                                               \
    } while (0)

  #define WRITET(BF) do {                                                             \
      *(int4*)&At[BF][adk][atq * 8] = abuf.v;                                         \
      *(int4*)&Vt[BF][vdv][vth * 16] = vbuf.v[0];                                     \
      *(int4*)&Vt[BF][vdv][vth * 16 + 8] = vbuf.v[1];                                 \
    } while (0)

  LOADT(0);
  __syncthreads();
  DECAY(0);
  WRITET(0);
  for (int kk = 0; kk < 16; ++kk) {
    int cur = kk & 1;
    if (kk < 15) LOADT(kk + 1);
    __syncthreads();
    bf16x8 af = *(const bf16x8*)&At[cur][w * 16 + r][q * 8];
    #pragma unroll
    for (int n = 0; n < 8; ++n) {
      bf16x8 vf = *(const bf16x8*)&Vt[cur][n * 16 + r][q * 8];
      acc[n] = __builtin_amdgcn_mfma_f32_16x16x32_bf16(af, vf, acc[n], 0, 0, 0);
    }
    if (kk < 15) DECAY(kk + 1);
    __syncthreads();
    if (kk < 15) WRITET(1 - cur);
  }
  #undef LOADT
  #undef DECAY
  #undef WRITET

  float* dst = part + ((size_t)(b * H_ + h) * 8 + s) * (DK_ * DV_);
  #pragma unroll
  for (int n = 0; n < 8; ++n)
    #pragma unroll
    for (int j = 0; j < 4; ++j)
      dst[(w * 16 + q * 4 + j) * DV_ + n * 16 + r] = acc[n][j];
}

// K7: out = exp(g_total)*state + sum over 8 splits. float4-vectorized.
__global__ __launch_bounds__(256) void k_final(const float* __restrict__ part,
                                               const float* __restrict__ gt,
                                               const float* __restrict__ st,
                                               float* __restrict__ out) {
  int i4 = blockIdx.x * 256 + threadIdx.x;
  int i = i4 * 4;
  int dv = i & 127, dk = (i >> 7) & 63, h = (i >> 13) & 15, b = i >> 17;
  size_t base = ((size_t)(b * H_ + h) * 8) * 8192 + dk * DV_ + dv;
  float4 sacc = {0.f, 0.f, 0.f, 0.f};
  #pragma unroll
  for (int sp = 0; sp < 8; ++sp) {
    float4 pv = *(const float4*)&part[base + (size_t)sp * 8192];
    sacc.x += pv.x; sacc.y += pv.y; sacc.z += pv.z; sacc.w += pv.w;
  }
  float eg = fexp(gt[b * HDK + h * DK_ + dk]);
  float4 stv = *(const float4*)&st[i];
  float4 o;
  o.x = eg * stv.x + sacc.x;
  o.y = eg * stv.y + sacc.y;
  o.z = eg * stv.z + sacc.z;
  o.w = eg * stv.w + sacc.w;
  *(float4*)&out[i] = o;
}

extern "C" void kernel_launch(void* const* d_in, const int* in_sizes, int n_in,
                              void* d_out, int out_size, void* d_ws, size_t ws_size,
                              hipStream_t stream) {
  const float* hs = (const float*)d_in[0];
  const float* st = (const float*)d_in[1];
  const float* nw = (const float*)d_in[2];
  const float* kw = (const float*)d_in[3];
  const float* vw = (const float*)d_in[4];
  const float* w1 = (const float*)d_in[5];
  const float* w2 = (const float*)d_in[6];
  const float* gb = (const float*)d_in[7];
  float* out = (float*)d_out;
  char* ws = (char*)d_ws;

  u16*  Wb  = (u16*)(ws + 0);              // 12,582,912
  u16*  xb  = (u16*)(ws + 12582912);       // 67,108,864 (dead after gemm)
  float* y  = (float*)(ws + 79691776);     //  1,048,576
  u16*  kv  = (u16*)(ws + 80740352);       // 100,663,296
  u16*  gkh = (u16*)(ws + 181403648);      // 33,554,432 (f16)
  float* ct = (float*)(ws + 214958080);    //  1,048,576
  float* co = (float*)(ws + 216006656);    //  1,048,576
  float* gt = (float*)(ws + 217055232);    //     16,384
  float* part = (float*)(ws + 12582912);          // reuse xb region (16.8 MB)

  k_cvtw<<<dim3(3072), dim3(256), 0, stream>>>(kw, vw, Wb);
  k_rms<<<dim3(4096), dim3(256), 0, stream>>>(hs, nw, w1, xb, y);
  k_gemm<<<dim3(768), dim3(512), 0, stream>>>(xb, Wb, kv);
  k_gkcs<<<dim3(1024), dim3(256), 0, stream>>>(y, w2, gb, gkh, ct);
  k_scan<<<dim3(16), dim3(512), 0, stream>>>(ct, co, gt);
  k_outer<<<dim3(8, 16, 4), dim3(256), 0, stream>>>(gkh, kv, co, gt, part);
  k_final<<<dim3(512), dim3(256), 0, stream>>>(part, gt, st, out);
}